// Round 3
// baseline (28511.847 us; speedup 1.0000x reference)
//
#include <hip/hip_runtime.h>

// ---------------------------------------------------------------------------
// VehicleTrajectoryDecoder: B=32, N=256, D=512, H=8 (dh=64), T=60, DFF=2048.
// R3: R1/R2 showed per-dispatch overhead (~25us) dominates: 304 vs 544
// dispatches both ~14.5ms. Collapse the 60-step loop into ONE persistent
// cooperative kernel (256 blocks x 256 thr) with a manual device-scope grid
// barrier; 9 barriers/step. 5 dispatches total.
// ---------------------------------------------------------------------------

#define NB 32
#define NN 256
#define DD 512
#define NH 8
#define DH 64
#define TT 60
#define DF 2048
#define NBLK 256

// ---- workspace layout (floats) --------------------------------------------
constexpr size_t SZ_KV  = (size_t)NB * NN * DD;
constexpr size_t SZ_SA  = (size_t)NB * TT * DD;
constexpr size_t SZ_ROW = (size_t)NB * DD;
constexpr size_t OFF_KS  = 0;
constexpr size_t OFF_VS  = OFF_KS  + SZ_KV;
constexpr size_t OFF_KC  = OFF_VS  + SZ_KV;
constexpr size_t OFF_VC  = OFF_KC  + SZ_KV;
constexpr size_t OFF_KST = OFF_VC  + SZ_KV;            // Ks transposed [b][d][n]
constexpr size_t OFF_KCT = OFF_KST + SZ_KV;            // Kc transposed [b][d][n]
constexpr size_t OFF_KSA = OFF_KCT + SZ_KV;            // self-attn K cache [b][t][d]
constexpr size_t OFF_VSA = OFF_KSA + SZ_SA;
constexpr size_t OFF_WT  = OFF_VSA + SZ_SA;            // 8 transposed 512x512 weights
constexpr size_t OFF_W1T = OFF_WT  + 8ull * DD * DD;   // [512][2048]
constexpr size_t OFF_W2T = OFF_W1T + (size_t)DD * DF;  // [2048][512]
constexpr size_t OFF_X   = OFF_W2T + (size_t)DF * DD;
constexpr size_t OFF_QSA = OFF_X   + SZ_ROW;
constexpr size_t OFF_QS  = OFF_QSA + SZ_ROW;
constexpr size_t OFF_ASA = OFF_QS  + SZ_ROW;
constexpr size_t OFF_ASP = OFF_ASA + SZ_ROW;
constexpr size_t OFF_ACA = OFF_ASP + SZ_ROW;
constexpr size_t OFF_U1  = OFF_ACA + SZ_ROW;
constexpr size_t OFF_Y1  = OFF_U1  + SZ_ROW;
constexpr size_t OFF_QC  = OFF_Y1  + SZ_ROW;
constexpr size_t OFF_U2  = OFF_QC  + SZ_ROW;
constexpr size_t OFF_CTX = OFF_U2  + SZ_ROW;
constexpr size_t OFF_U3  = OFF_CTX + SZ_ROW;
constexpr size_t OFF_H   = OFF_U3  + SZ_ROW;           // hbuf [32][2048]
constexpr size_t OFF_BAR = OFF_H   + (size_t)NB * DF;  // barrier counter (1 u32)

// ---- params for the persistent kernel --------------------------------------
struct Params {
  const float *pe;
  const float *sa_bq, *sa_bk, *sa_bv, *sa_bo;
  const float *s_bq, *s_bo, *ca_bq, *ca_bo;
  const float *ln1w, *ln1b, *ln2w, *ln2b, *ln3w, *ln3b;
  const float *b1, *b2, *Wout, *bout;
  const float *wt8, *W1t, *W2t;
  const float *KsT, *KcT, *Vs, *Vc;
  float *Ksa, *Vsa, *xcur, *qsa, *qs, *aSA, *aSP, *aCA;
  float *u1, *y1, *qc, *u2, *ctx, *u3, *hbuf;
  float *out;
  unsigned *bar;
};

// ---- device helpers ---------------------------------------------------------
__device__ __forceinline__ void gsync(unsigned* bar, unsigned& round, int tid) {
  __syncthreads();
  round++;
  if (tid == 0) {
    __threadfence();  // release this block's prior global writes (device scope)
    __hip_atomic_fetch_add(bar, 1u, __ATOMIC_RELEASE, __HIP_MEMORY_SCOPE_AGENT);
    unsigned target = round * (unsigned)NBLK;
    while (__hip_atomic_load(bar, __ATOMIC_ACQUIRE, __HIP_MEMORY_SCOPE_AGENT) < target)
      __builtin_amdgcn_s_sleep(1);
    __threadfence();  // acquire other blocks' writes
  }
  __syncthreads();
}

// stage 4 contiguous rows of 512 floats into LDS (2048 floats)
__device__ __forceinline__ void stage4(float* sX, const float* src, int tid) {
  #pragma unroll
  for (int q = 0; q < 2; q++) {
    int f = q * 1024 + tid * 4;
    *(float4*)(sX + f) = *(const float4*)(src + f);
  }
}

// in-place LayerNorm of 4 LDS rows (wave w handles row w)
__device__ __forceinline__ void ln4(float* sX, const float* w, const float* b,
                                    float* lm, float* li, int tid) {
  int wv = tid >> 6, lane = tid & 63;
  float s = 0.f, q = 0.f;
  #pragma unroll
  for (int i = 0; i < 8; i++) {
    float v = sX[wv * DD + lane + i * 64];
    s += v; q += v * v;
  }
  #pragma unroll
  for (int m = 32; m >= 1; m >>= 1) { s += __shfl_xor(s, m); q += __shfl_xor(q, m); }
  if (lane == 0) {
    float mm = s * (1.0f / 512.0f);
    lm[wv] = mm;
    li[wv] = rsqrtf(q * (1.0f / 512.0f) - mm * mm + 1e-5f);
  }
  __syncthreads();
  float w0 = w[tid], w1 = w[tid + 256], b0 = b[tid], b1 = b[tid + 256];
  #pragma unroll
  for (int r = 0; r < 4; r++) {
    sX[r * DD + tid]       = (sX[r * DD + tid]       - lm[r]) * li[r] * w0 + b0;
    sX[r * DD + tid + 256] = (sX[r * DD + tid + 256] - lm[r]) * li[r] * w1 + b1;
  }
  __syncthreads();
}

// GEMV: 1 output per thread; 4 rows staged in sX; weight column-major [k][col]
__device__ __forceinline__ float gemv1(const float* sX, const float* wp,
                                       int ldw, int tid) {
  const float* xr = sX + (tid >> 6) * DD;
  float acc = 0.f;
  for (int k = 0; k < DD; k += 4) {
    float w0 = wp[(size_t)(k + 0) * ldw];
    float w1 = wp[(size_t)(k + 1) * ldw];
    float w2 = wp[(size_t)(k + 2) * ldw];
    float w3 = wp[(size_t)(k + 3) * ldw];
    float4 xv = *(const float4*)(xr + k);
    acc += xv.x * w0 + xv.y * w1 + xv.z * w2 + xv.w * w3;
  }
  return acc;
}

// attention over 256 keys for one (b,h); KT [d][n], V [n][512]
__device__ __forceinline__ void attn_unit(
    const float* __restrict__ qrow, int h,
    const float* __restrict__ KT, const float* __restrict__ V,
    float* __restrict__ outrow,
    float* sQh, float* sP, float* sB, float* redM, float* redS, int tid) {
  int w = tid >> 6, lane = tid & 63;
  if (tid < DH) sQh[tid] = qrow[h * DH + tid];
  __syncthreads();
  const float* kp = KT + (size_t)(h * DH) * NN + tid;
  float a = 0.f;
  #pragma unroll 8
  for (int i = 0; i < DH; i++) a += sQh[i] * kp[(size_t)i * NN];
  a *= 0.125f;
  float m = a;
  #pragma unroll
  for (int s = 32; s >= 1; s >>= 1) m = fmaxf(m, __shfl_xor(m, s));
  if (lane == 0) redM[w] = m;
  __syncthreads();
  m = fmaxf(fmaxf(redM[0], redM[1]), fmaxf(redM[2], redM[3]));
  float e = __expf(a - m);
  float ss = e;
  #pragma unroll
  for (int s = 32; s >= 1; s >>= 1) ss += __shfl_xor(ss, s);
  if (lane == 0) redS[w] = ss;
  sP[tid] = e;
  __syncthreads();
  float inv = 1.f / (redS[0] + redS[1] + redS[2] + redS[3]);
  int q4 = tid >> 6, d = tid & 63;
  const float* vp = V + (size_t)(q4 * 64) * DD + h * DH + d;
  float acc = 0.f;
  #pragma unroll 4
  for (int n = 0; n < 64; n++) acc += sP[q4 * 64 + n] * vp[(size_t)n * DD];
  sB[tid] = acc;
  __syncthreads();
  if (tid < 64)
    outrow[h * DH + tid] = (sB[tid] + sB[64 + tid] + sB[128 + tid] + sB[192 + tid]) * inv;
  __syncthreads();
}

// ---- the persistent decode kernel ------------------------------------------
__global__ __launch_bounds__(256) void decode_persistent(Params P) {
  __shared__ __align__(16) float sX[4 * DD];   // 8 KB staging
  __shared__ float sAux[128];
  int tid = threadIdx.x;
  int bid = blockIdx.x;
  unsigned round = 0;

  float* lm   = sAux;        // 8
  float* li   = sAux + 8;    // 8
  float* red  = sAux + 16;   // 24
  float* redM = sAux + 16;   // 4
  float* redS = sAux + 24;   // 4
  float* sInv = sAux + 40;   // 8
  float* sQh  = sAux + 48;   // 64

  for (int t = 0; t < TT; t++) {
    // ---- Phase A: proj4 (qsa, Ksa[t], Vsa[t], qs) --------------------------
    {
      int m = bid >> 6, jb = (bid >> 3) & 7, bg = bid & 7;
      stage4(sX, P.xcur + (size_t)(bg * 4) * DD, tid);
      __syncthreads();
      const int wmap[4] = {0, 1, 2, 6};
      int col = jb * 64 + (tid & 63);
      int b = bg * 4 + (tid >> 6);
      const float* wp = P.wt8 + (size_t)wmap[m] * DD * DD + col;
      float acc = gemv1(sX, wp, DD, tid);
      if (m == 0)      P.qsa[(size_t)b * DD + col] = acc + P.sa_bq[col];
      else if (m == 1) P.Ksa[((size_t)b * TT + t) * DD + col] = acc + P.sa_bk[col];
      else if (m == 2) P.Vsa[((size_t)b * TT + t) * DD + col] = acc + P.sa_bv[col];
      else             P.qs[(size_t)b * DD + col] = acc + P.s_bq[col];
    }
    gsync(P.bar, round, tid);

    // ---- Phase B: self-attn (32 blocks) + spatial attn (224 blocks) --------
    if (bid < NB) {
      int b = bid, L = t + 1;
      float* sQ = sX; float* sP = sX + DD;
      sQ[tid] = P.qsa[(size_t)b * DD + tid];
      sQ[tid + 256] = P.qsa[(size_t)b * DD + tid + 256];
      __syncthreads();
      for (int p = tid; p < NH * L; p += 256) {
        int h = p / L, j = p - h * L;
        const float* kp = P.Ksa + ((size_t)b * TT + j) * DD + h * DH;
        const float* qp = sQ + h * DH;
        float a = 0.f;
        #pragma unroll
        for (int i = 0; i < DH; i += 4) {
          float4 kv = *(const float4*)(kp + i);
          a += qp[i] * kv.x + qp[i + 1] * kv.y + qp[i + 2] * kv.z + qp[i + 3] * kv.w;
        }
        sP[h * 64 + j] = a * 0.125f;
      }
      __syncthreads();
      if (tid < NH) {
        float mx = -1e30f;
        for (int j = 0; j < L; j++) mx = fmaxf(mx, sP[tid * 64 + j]);
        float s = 0.f;
        for (int j = 0; j < L; j++) {
          float e = __expf(sP[tid * 64 + j] - mx);
          sP[tid * 64 + j] = e;
          s += e;
        }
        sInv[tid] = 1.f / s;
      }
      __syncthreads();
      for (int d = tid; d < DD; d += 256) {
        int h = d >> 6;
        const float* vp = P.Vsa + (size_t)b * TT * DD + d;
        float a = 0.f;
        for (int j = 0; j < L; j++) a += sP[h * 64 + j] * vp[(size_t)j * DD];
        P.aSA[(size_t)b * DD + d] = a * sInv[h];
      }
    } else {
      for (int u = bid - NB; u < NB * NH; u += NBLK - NB) {
        int b = u >> 3, h = u & 7;
        attn_unit(P.qs + (size_t)b * DD, h, P.KsT + (size_t)b * NN * DD,
                  P.Vs + (size_t)b * NN * DD, P.aSP + (size_t)b * DD,
                  sQh, sX + DD, sX + 2 * DD, redM, redS, tid);
      }
    }
    gsync(P.bar, round, tid);

    // ---- Phase C: u1 = aSA@saWo + sa_bo + x ; ctx = aSP@sWo + s_bo ---------
    if (bid < 128) {
      int mz = bid >> 6, jb = (bid >> 3) & 7, bg = bid & 7;
      const float* src = (mz ? P.aSP : P.aSA) + (size_t)(bg * 4) * DD;
      stage4(sX, src, tid);
      __syncthreads();
      int col = jb * 64 + (tid & 63);
      int b = bg * 4 + (tid >> 6);
      const float* wp = P.wt8 + (size_t)(mz ? 7 : 3) * DD * DD + col;
      float acc = gemv1(sX, wp, DD, tid);
      if (mz == 0)
        P.u1[(size_t)b * DD + col] = acc + P.sa_bo[col] + P.xcur[(size_t)b * DD + col];
      else
        P.ctx[(size_t)b * DD + col] = acc + P.s_bo[col];
    }
    gsync(P.bar, round, tid);

    // ---- Phase D: LN1(u1) -> y1 ; qc = y1@caWq + ca_bq ---------------------
    if (bid < 64) {
      int jb = bid >> 3, bg = bid & 7;
      stage4(sX, P.u1 + (size_t)(bg * 4) * DD, tid);
      __syncthreads();
      ln4(sX, P.ln1w, P.ln1b, lm, li, tid);
      if (jb == 0) {
        #pragma unroll
        for (int r = 0; r < 4; r++) {
          P.y1[(size_t)(bg * 4 + r) * DD + tid] = sX[r * DD + tid];
          P.y1[(size_t)(bg * 4 + r) * DD + tid + 256] = sX[r * DD + tid + 256];
        }
      }
      int col = jb * 64 + (tid & 63);
      int b = bg * 4 + (tid >> 6);
      const float* wp = P.wt8 + 4ull * DD * DD + col;
      float acc = gemv1(sX, wp, DD, tid);
      P.qc[(size_t)b * DD + col] = acc + P.ca_bq[col];
    }
    gsync(P.bar, round, tid);

    // ---- Phase E: cross-attn, one (b,h) per block --------------------------
    {
      int b = bid >> 3, h = bid & 7;
      attn_unit(P.qc + (size_t)b * DD, h, P.KcT + (size_t)b * NN * DD,
                P.Vc + (size_t)b * NN * DD, P.aCA + (size_t)b * DD,
                sQh, sX + DD, sX + 2 * DD, redM, redS, tid);
    }
    gsync(P.bar, round, tid);

    // ---- Phase F: u2 = aCA@caWo + ca_bo + y1 -------------------------------
    if (bid < 64) {
      int jb = bid >> 3, bg = bid & 7;
      stage4(sX, P.aCA + (size_t)(bg * 4) * DD, tid);
      __syncthreads();
      int col = jb * 64 + (tid & 63);
      int b = bg * 4 + (tid >> 6);
      const float* wp = P.wt8 + 5ull * DD * DD + col;
      float acc = gemv1(sX, wp, DD, tid);
      P.u2[(size_t)b * DD + col] = acc + P.ca_bo[col] + P.y1[(size_t)b * DD + col];
    }
    gsync(P.bar, round, tid);

    // ---- Phase G: LN2(u2)=z ; u3 = z + b2 (jb==0) ; hbuf = relu(z@W1+b1) ---
    {
      int jb = bid >> 3, bg = bid & 7;  // jb 0..31 (64 cols of 2048)
      stage4(sX, P.u2 + (size_t)(bg * 4) * DD, tid);
      __syncthreads();
      ln4(sX, P.ln2w, P.ln2b, lm, li, tid);
      if (jb == 0) {
        float f0 = P.b2[tid], f1 = P.b2[tid + 256];
        #pragma unroll
        for (int r = 0; r < 4; r++) {
          P.u3[(size_t)(bg * 4 + r) * DD + tid] = sX[r * DD + tid] + f0;
          P.u3[(size_t)(bg * 4 + r) * DD + tid + 256] = sX[r * DD + tid + 256] + f1;
        }
      }
      int col = jb * 64 + (tid & 63);   // [0, 2048)
      int b = bg * 4 + (tid >> 6);
      const float* wp = P.W1t + col;
      float acc = gemv1(sX, wp, DF, tid);
      P.hbuf[(size_t)b * DF + col] = fmaxf(acc + P.b1[col], 0.f);
    }
    gsync(P.bar, round, tid);

    // ---- Phase H: u3 += hbuf@W2 (split-k x4, atomic) -----------------------
    {
      int jb = bid & 7, bg = (bid >> 3) & 7, ks = bid >> 6;
      #pragma unroll
      for (int q = 0; q < 2; q++) {
        int f = q * 1024 + tid * 4, r = f >> 9, c = f & 511;
        *(float4*)(sX + f) =
            *(const float4*)(P.hbuf + (size_t)(bg * 4 + r) * DF + ks * 512 + c);
      }
      __syncthreads();
      int col = jb * 64 + (tid & 63);
      int b = bg * 4 + (tid >> 6);
      const float* wp = P.W2t + (size_t)(ks * 512) * DD + col;
      float acc = gemv1(sX, wp, DD, tid);
      atomicAdd(&P.u3[(size_t)b * DD + col], acc);
    }
    gsync(P.bar, round, tid);

    // ---- Phase I: nxt = LN3(u3) + ctx ; out ; xcur = nxt + pe[t+1] ---------
    if (bid < NB) {
      int b = bid, wv = tid >> 6, lane = tid & 63;
      float u0 = P.u3[(size_t)b * DD + tid];
      float u1v = P.u3[(size_t)b * DD + tid + 256];
      float s = u0 + u1v, q = u0 * u0 + u1v * u1v;
      #pragma unroll
      for (int m = 32; m >= 1; m >>= 1) { s += __shfl_xor(s, m); q += __shfl_xor(q, m); }
      if (lane == 0) { red[wv] = s; red[8 + wv] = q; }
      __syncthreads();
      if (tid == 0) {
        float ss = red[0] + red[1] + red[2] + red[3];
        float qq = red[8] + red[9] + red[10] + red[11];
        float mm = ss * (1.0f / 512.0f);
        red[16] = mm;
        red[17] = rsqrtf(qq * (1.0f / 512.0f) - mm * mm + 1e-5f);
      }
      __syncthreads();
      float mean = red[16], inv = red[17];
      float n0 = (u0 - mean) * inv * P.ln3w[tid] + P.ln3b[tid] +
                 P.ctx[(size_t)b * DD + tid];
      float n1 = (u1v - mean) * inv * P.ln3w[tid + 256] + P.ln3b[tid + 256] +
                 P.ctx[(size_t)b * DD + tid + 256];
      sX[tid] = n0; sX[tid + 256] = n1;
      float p0 = (t < TT - 1) ? P.pe[(size_t)(t + 1) * DD + tid] : 0.f;
      float p1 = (t < TT - 1) ? P.pe[(size_t)(t + 1) * DD + tid + 256] : 0.f;
      P.xcur[(size_t)b * DD + tid] = n0 + p0;
      P.xcur[(size_t)b * DD + tid + 256] = n1 + p1;
      __syncthreads();
      int c = tid >> 7, l = tid & 127;
      float a = 0.f;
      #pragma unroll
      for (int i = 0; i < 4; i++) a += sX[l + i * 128] * P.Wout[(size_t)c * DD + l + i * 128];
      #pragma unroll
      for (int m = 32; m >= 1; m >>= 1) a += __shfl_xor(a, m);
      if ((tid & 63) == 0) red[tid >> 6] = a;
      __syncthreads();
      if (tid == 0)   P.out[((size_t)b * TT + t) * 2 + 0] = red[0] + red[1] + P.bout[0];
      if (tid == 128) P.out[((size_t)b * TT + t) * 2 + 1] = red[2] + red[3] + P.bout[1];
    }
    gsync(P.bar, round, tid);
  }
}

// ---- precompute kernels (unchanged from R2) ---------------------------------
struct TPItem { const float* in; float* out; int R; int C; };
struct TPArgs { TPItem m[10]; };

__global__ __launch_bounds__(256) void transpose_many(TPArgs args) {
  const TPItem t = args.m[blockIdx.z];
  int r0 = blockIdx.x * 32, c0 = blockIdx.y * 32;
  if (r0 >= t.R || c0 >= t.C) return;
  __shared__ float tile[32][33];
  int tid = threadIdx.x;
  int i = tid >> 3, j4 = (tid & 7) * 4;
  float4 v = *(const float4*)(t.in + (size_t)(r0 + i) * t.C + c0 + j4);
  tile[i][j4] = v.x; tile[i][j4 + 1] = v.y; tile[i][j4 + 2] = v.z; tile[i][j4 + 3] = v.w;
  __syncthreads();
  float4 o;
  o.x = tile[j4][i]; o.y = tile[j4 + 1][i]; o.z = tile[j4 + 2][i]; o.w = tile[j4 + 3][i];
  *(float4*)(t.out + (size_t)(c0 + i) * t.R + r0 + j4) = o;
}

__global__ __launch_bounds__(256) void transpose_kv(const float* __restrict__ Ks,
                                                    const float* __restrict__ Kc,
                                                    float* __restrict__ KsT,
                                                    float* __restrict__ KcT) {
  int z = blockIdx.z;
  int b = z >> 1;
  const float* in = ((z & 1) ? Kc : Ks) + (size_t)b * NN * DD;
  float* out = ((z & 1) ? KcT : KsT) + (size_t)b * NN * DD;
  int r0 = blockIdx.x * 32, c0 = blockIdx.y * 32;
  __shared__ float tile[32][33];
  int tid = threadIdx.x;
  int i = tid >> 3, j4 = (tid & 7) * 4;
  float4 v = *(const float4*)(in + (size_t)(r0 + i) * DD + c0 + j4);
  tile[i][j4] = v.x; tile[i][j4 + 1] = v.y; tile[i][j4 + 2] = v.z; tile[i][j4 + 3] = v.w;
  __syncthreads();
  float4 o;
  o.x = tile[j4][i]; o.y = tile[j4 + 1][i]; o.z = tile[j4 + 2][i]; o.w = tile[j4 + 3][i];
  *(float4*)(out + (size_t)(c0 + i) * NN + r0 + j4) = o;
}

__global__ __launch_bounds__(256) void init_x(const float* __restrict__ hv0,
                                              const float* __restrict__ pe,
                                              float* __restrict__ xcur,
                                              unsigned* __restrict__ bar) {
  int i = blockIdx.x * 256 + threadIdx.x;
  xcur[i] = hv0[i] + pe[i & (DD - 1)];
  if (i == 0) bar[0] = 0u;
}

__global__ __launch_bounds__(256) void gemm_kv(
    const float* __restrict__ A,
    const float* __restrict__ W0, const float* __restrict__ W1_,
    const float* __restrict__ W2_, const float* __restrict__ W3_,
    const float* __restrict__ b0, const float* __restrict__ b1_,
    const float* __restrict__ b2_, const float* __restrict__ b3_,
    float* __restrict__ O0, float* __restrict__ O1,
    float* __restrict__ O2, float* __restrict__ O3) {
  __shared__ __align__(16) float As[8][128];
  __shared__ __align__(16) float Bs[8][128];
  int tid = threadIdx.x;
  int bx = blockIdx.x, by = blockIdx.y;
  int mm = bx >> 2;
  int col0 = (bx & 3) * 128;
  const float* W = mm == 0 ? W0 : mm == 1 ? W1_ : mm == 2 ? W2_ : W3_;
  const float* bias = mm == 0 ? b0 : mm == 1 ? b1_ : mm == 2 ? b2_ : b3_;
  float* O = mm == 0 ? O0 : mm == 1 ? O1 : mm == 2 ? O2 : O3;
  int tx = tid & 15, ty = tid >> 4;
  int m0 = by * 128;
  int lr = tid >> 1, lk = (tid & 1) * 4;
  const float* Ap = A + (size_t)(m0 + lr) * DD + lk;
  const float* Wp = W + (size_t)(col0 + lr) * DD + lk;
  float c[8][8] = {};
  for (int k0 = 0; k0 < DD; k0 += 8) {
    float4 av = *(const float4*)(Ap + k0);
    float4 wv = *(const float4*)(Wp + k0);
    __syncthreads();
    As[lk + 0][lr] = av.x; As[lk + 1][lr] = av.y; As[lk + 2][lr] = av.z; As[lk + 3][lr] = av.w;
    Bs[lk + 0][lr] = wv.x; Bs[lk + 1][lr] = wv.y; Bs[lk + 2][lr] = wv.z; Bs[lk + 3][lr] = wv.w;
    __syncthreads();
    #pragma unroll
    for (int k = 0; k < 8; k++) {
      float a[8], bb[8];
      *(float4*)&a[0] = *(const float4*)&As[k][ty * 8];
      *(float4*)&a[4] = *(const float4*)&As[k][ty * 8 + 4];
      *(float4*)&bb[0] = *(const float4*)&Bs[k][tx * 8];
      *(float4*)&bb[4] = *(const float4*)&Bs[k][tx * 8 + 4];
      #pragma unroll
      for (int i = 0; i < 8; i++)
        #pragma unroll
        for (int j = 0; j < 8; j++) c[i][j] += a[i] * bb[j];
    }
  }
  const float* bp = bias + col0 + tx * 8;
  for (int i = 0; i < 8; i++) {
    int row = m0 + ty * 8 + i;
    float* op = O + (size_t)row * DD + col0 + tx * 8;
    #pragma unroll
    for (int jq = 0; jq < 8; jq += 4) {
      float4 v;
      v.x = c[i][jq + 0] + bp[jq + 0];
      v.y = c[i][jq + 1] + bp[jq + 1];
      v.z = c[i][jq + 2] + bp[jq + 2];
      v.w = c[i][jq + 3] + bp[jq + 3];
      *(float4*)(op + jq) = v;
    }
  }
}

// ---------------------------------------------------------------------------
extern "C" void kernel_launch(void* const* d_in, const int* in_sizes, int n_in,
                              void* d_out, int out_size, void* d_ws, size_t ws_size,
                              hipStream_t stream) {
  const float* H_v_all = (const float*)d_in[0];
  const float* H_v0    = (const float*)d_in[1];
  const float* pe      = (const float*)d_in[2];
  const float* s_Wq = (const float*)d_in[3];
  const float* s_Wk = (const float*)d_in[4];
  const float* s_Wv = (const float*)d_in[5];
  const float* s_Wo = (const float*)d_in[6];
  const float* s_bq = (const float*)d_in[7];
  const float* s_bk = (const float*)d_in[8];
  const float* s_bv = (const float*)d_in[9];
  const float* s_bo = (const float*)d_in[10];
  const float* sa_Wq = (const float*)d_in[11];
  const float* sa_Wk = (const float*)d_in[12];
  const float* sa_Wv = (const float*)d_in[13];
  const float* sa_Wo = (const float*)d_in[14];
  const float* sa_bq = (const float*)d_in[15];
  const float* sa_bk = (const float*)d_in[16];
  const float* sa_bv = (const float*)d_in[17];
  const float* sa_bo = (const float*)d_in[18];
  const float* ca_Wq = (const float*)d_in[19];
  const float* ca_Wk = (const float*)d_in[20];
  const float* ca_Wv = (const float*)d_in[21];
  const float* ca_Wo = (const float*)d_in[22];
  const float* ca_bq = (const float*)d_in[23];
  const float* ca_bk = (const float*)d_in[24];
  const float* ca_bv = (const float*)d_in[25];
  const float* ca_bo = (const float*)d_in[26];
  const float* ln1w = (const float*)d_in[27];
  const float* ln1b = (const float*)d_in[28];
  const float* ln2w = (const float*)d_in[29];
  const float* ln2b = (const float*)d_in[30];
  const float* ln3w = (const float*)d_in[31];
  const float* ln3b = (const float*)d_in[32];
  const float* W1   = (const float*)d_in[33];
  const float* b1   = (const float*)d_in[34];
  const float* W2   = (const float*)d_in[35];
  const float* b2   = (const float*)d_in[36];
  const float* Wout = (const float*)d_in[37];
  const float* bout = (const float*)d_in[38];

  float* ws  = (float*)d_ws;
  float* Ks  = ws + OFF_KS;
  float* Vs  = ws + OFF_VS;
  float* Kc  = ws + OFF_KC;
  float* Vc  = ws + OFF_VC;
  float* KsT = ws + OFF_KST;
  float* KcT = ws + OFF_KCT;
  float* Ksa = ws + OFF_KSA;
  float* Vsa = ws + OFF_VSA;
  float* wt8 = ws + OFF_WT;
  float* W1t = ws + OFF_W1T;
  float* W2t = ws + OFF_W2T;
  float* xcur = ws + OFF_X;
  unsigned* bar = (unsigned*)(ws + OFF_BAR);

  // --- precompute -----------------------------------------------------------
  TPArgs tp;
  tp.m[0] = {sa_Wq, wt8 + 0ull * DD * DD, DD, DD};
  tp.m[1] = {sa_Wk, wt8 + 1ull * DD * DD, DD, DD};
  tp.m[2] = {sa_Wv, wt8 + 2ull * DD * DD, DD, DD};
  tp.m[3] = {sa_Wo, wt8 + 3ull * DD * DD, DD, DD};
  tp.m[4] = {ca_Wq, wt8 + 4ull * DD * DD, DD, DD};
  tp.m[5] = {ca_Wo, wt8 + 5ull * DD * DD, DD, DD};
  tp.m[6] = {s_Wq,  wt8 + 6ull * DD * DD, DD, DD};
  tp.m[7] = {s_Wo,  wt8 + 7ull * DD * DD, DD, DD};
  tp.m[8] = {W1, W1t, DF, DD};
  tp.m[9] = {W2, W2t, DD, DF};
  hipLaunchKernelGGL(transpose_many, dim3(64, 64, 10), dim3(256), 0, stream, tp);

  hipLaunchKernelGGL(gemm_kv, dim3(16, 64), dim3(256), 0, stream,
                     H_v_all, s_Wk, s_Wv, ca_Wk, ca_Wv,
                     s_bk, s_bv, ca_bk, ca_bv, Ks, Vs, Kc, Vc);

  hipLaunchKernelGGL(transpose_kv, dim3(8, 16, 64), dim3(256), 0, stream,
                     Ks, Kc, KsT, KcT);

  hipLaunchKernelGGL(init_x, dim3(64), dim3(256), 0, stream, H_v0, pe, xcur, bar);

  // --- one persistent kernel for all 60 steps -------------------------------
  Params P;
  P.pe = pe;
  P.sa_bq = sa_bq; P.sa_bk = sa_bk; P.sa_bv = sa_bv; P.sa_bo = sa_bo;
  P.s_bq = s_bq; P.s_bo = s_bo; P.ca_bq = ca_bq; P.ca_bo = ca_bo;
  P.ln1w = ln1w; P.ln1b = ln1b; P.ln2w = ln2w; P.ln2b = ln2b;
  P.ln3w = ln3w; P.ln3b = ln3b;
  P.b1 = b1; P.b2 = b2; P.Wout = Wout; P.bout = bout;
  P.wt8 = wt8; P.W1t = W1t; P.W2t = W2t;
  P.KsT = KsT; P.KcT = KcT; P.Vs = Vs; P.Vc = Vc;
  P.Ksa = Ksa; P.Vsa = Vsa; P.xcur = xcur;
  P.qsa = ws + OFF_QSA; P.qs = ws + OFF_QS;
  P.aSA = ws + OFF_ASA; P.aSP = ws + OFF_ASP; P.aCA = ws + OFF_ACA;
  P.u1 = ws + OFF_U1; P.y1 = ws + OFF_Y1; P.qc = ws + OFF_QC;
  P.u2 = ws + OFF_U2; P.ctx = ws + OFF_CTX; P.u3 = ws + OFF_U3;
  P.hbuf = ws + OFF_H;
  P.out = (float*)d_out;
  P.bar = bar;

  void* kargs[] = { (void*)&P };
  hipLaunchCooperativeKernel((void*)decode_persistent, dim3(NBLK), dim3(256),
                             kargs, 0, stream);
}

// Round 4
// 12336.246 us; speedup vs baseline: 2.3112x; 2.3112x over previous
//
#include <hip/hip_runtime.h>

// ---------------------------------------------------------------------------
// VehicleTrajectoryDecoder: B=32, N=256, D=512, H=8 (dh=64), T=60, DFF=2048.
// R4: R3's persistent kernel was correct but its grid barrier serialized 256
// same-line atomic RMWs (~51us/barrier x 540 = 27.6ms, VALUBusy 2.2%).
// Replace with a master-block flag barrier: per-block padded arrival flags
// (parallel stores), block 0 polls 255 lines with 255 threads, one release
// word. Phase/work code unchanged from R3.
// ---------------------------------------------------------------------------

#define NB 32
#define NN 256
#define DD 512
#define NH 8
#define DH 64
#define TT 60
#define DF 2048
#define NBLK 256
#define FLAG_STRIDE 32   // 32 u32 = 128B line per block flag

// ---- workspace layout (floats) --------------------------------------------
constexpr size_t SZ_KV  = (size_t)NB * NN * DD;
constexpr size_t SZ_SA  = (size_t)NB * TT * DD;
constexpr size_t SZ_ROW = (size_t)NB * DD;
constexpr size_t OFF_KS  = 0;
constexpr size_t OFF_VS  = OFF_KS  + SZ_KV;
constexpr size_t OFF_KC  = OFF_VS  + SZ_KV;
constexpr size_t OFF_VC  = OFF_KC  + SZ_KV;
constexpr size_t OFF_KST = OFF_VC  + SZ_KV;            // Ks transposed [b][d][n]
constexpr size_t OFF_KCT = OFF_KST + SZ_KV;            // Kc transposed [b][d][n]
constexpr size_t OFF_KSA = OFF_KCT + SZ_KV;            // self-attn K cache [b][t][d]
constexpr size_t OFF_VSA = OFF_KSA + SZ_SA;
constexpr size_t OFF_WT  = OFF_VSA + SZ_SA;            // 8 transposed 512x512 weights
constexpr size_t OFF_W1T = OFF_WT  + 8ull * DD * DD;   // [512][2048]
constexpr size_t OFF_W2T = OFF_W1T + (size_t)DD * DF;  // [2048][512]
constexpr size_t OFF_X   = OFF_W2T + (size_t)DF * DD;
constexpr size_t OFF_QSA = OFF_X   + SZ_ROW;
constexpr size_t OFF_QS  = OFF_QSA + SZ_ROW;
constexpr size_t OFF_ASA = OFF_QS  + SZ_ROW;
constexpr size_t OFF_ASP = OFF_ASA + SZ_ROW;
constexpr size_t OFF_ACA = OFF_ASP + SZ_ROW;
constexpr size_t OFF_U1  = OFF_ACA + SZ_ROW;
constexpr size_t OFF_Y1  = OFF_U1  + SZ_ROW;
constexpr size_t OFF_QC  = OFF_Y1  + SZ_ROW;
constexpr size_t OFF_U2  = OFF_QC  + SZ_ROW;
constexpr size_t OFF_CTX = OFF_U2  + SZ_ROW;
constexpr size_t OFF_U3  = OFF_CTX + SZ_ROW;
constexpr size_t OFF_H   = OFF_U3  + SZ_ROW;           // hbuf [32][2048]
constexpr size_t OFF_FLG = OFF_H   + (size_t)NB * DF;  // 256 padded flags + rel
// flags: u32[256*32]; rel: u32 at index 8192 (own 128B line). 33KB.

// ---- params for the persistent kernel --------------------------------------
struct Params {
  const float *pe;
  const float *sa_bq, *sa_bk, *sa_bv, *sa_bo;
  const float *s_bq, *s_bo, *ca_bq, *ca_bo;
  const float *ln1w, *ln1b, *ln2w, *ln2b, *ln3w, *ln3b;
  const float *b1, *b2, *Wout, *bout;
  const float *wt8, *W1t, *W2t;
  const float *KsT, *KcT, *Vs, *Vc;
  float *Ksa, *Vsa, *xcur, *qsa, *qs, *aSA, *aSP, *aCA;
  float *u1, *y1, *qc, *u2, *ctx, *u3, *hbuf;
  float *out;
  unsigned *flags;   // per-block arrival flags, 128B stride
  unsigned *rel;     // single release word
};

// ---- grid barrier: master-block flag design (no same-line RMW contention) --
__device__ __forceinline__ void gsync(unsigned* flags, unsigned* rel,
                                      unsigned& round, int tid, int bid) {
  __syncthreads();
  round++;
  if (bid == 0) {
    if (tid > 0 && tid < NBLK) {  // thread i polls block i's flag (own line)
      while (__hip_atomic_load(&flags[(size_t)tid * FLAG_STRIDE],
                               __ATOMIC_RELAXED, __HIP_MEMORY_SCOPE_AGENT) < round)
        __builtin_amdgcn_s_sleep(1);
    }
    __syncthreads();
    if (tid == 0) {
      __threadfence();  // make all blocks' writes visible before release
      __hip_atomic_store(rel, round, __ATOMIC_RELAXED, __HIP_MEMORY_SCOPE_AGENT);
    }
  } else {
    if (tid == 0) {
      __threadfence();  // release this block's prior global writes
      __hip_atomic_store(&flags[(size_t)bid * FLAG_STRIDE], round,
                         __ATOMIC_RELAXED, __HIP_MEMORY_SCOPE_AGENT);
      while (__hip_atomic_load(rel, __ATOMIC_RELAXED,
                               __HIP_MEMORY_SCOPE_AGENT) < round)
        __builtin_amdgcn_s_sleep(1);
      __threadfence();  // acquire: invalidate stale lines before block reads
    }
  }
  __syncthreads();
}

// stage 4 contiguous rows of 512 floats into LDS (2048 floats)
__device__ __forceinline__ void stage4(float* sX, const float* src, int tid) {
  #pragma unroll
  for (int q = 0; q < 2; q++) {
    int f = q * 1024 + tid * 4;
    *(float4*)(sX + f) = *(const float4*)(src + f);
  }
}

// in-place LayerNorm of 4 LDS rows (wave w handles row w)
__device__ __forceinline__ void ln4(float* sX, const float* w, const float* b,
                                    float* lm, float* li, int tid) {
  int wv = tid >> 6, lane = tid & 63;
  float s = 0.f, q = 0.f;
  #pragma unroll
  for (int i = 0; i < 8; i++) {
    float v = sX[wv * DD + lane + i * 64];
    s += v; q += v * v;
  }
  #pragma unroll
  for (int m = 32; m >= 1; m >>= 1) { s += __shfl_xor(s, m); q += __shfl_xor(q, m); }
  if (lane == 0) {
    float mm = s * (1.0f / 512.0f);
    lm[wv] = mm;
    li[wv] = rsqrtf(q * (1.0f / 512.0f) - mm * mm + 1e-5f);
  }
  __syncthreads();
  float w0 = w[tid], w1 = w[tid + 256], b0 = b[tid], b1 = b[tid + 256];
  #pragma unroll
  for (int r = 0; r < 4; r++) {
    sX[r * DD + tid]       = (sX[r * DD + tid]       - lm[r]) * li[r] * w0 + b0;
    sX[r * DD + tid + 256] = (sX[r * DD + tid + 256] - lm[r]) * li[r] * w1 + b1;
  }
  __syncthreads();
}

// GEMV: 1 output per thread; 4 rows staged in sX; weight column-major [k][col]
__device__ __forceinline__ float gemv1(const float* sX, const float* wp,
                                       int ldw, int tid) {
  const float* xr = sX + (tid >> 6) * DD;
  float acc = 0.f;
  for (int k = 0; k < DD; k += 4) {
    float w0 = wp[(size_t)(k + 0) * ldw];
    float w1 = wp[(size_t)(k + 1) * ldw];
    float w2 = wp[(size_t)(k + 2) * ldw];
    float w3 = wp[(size_t)(k + 3) * ldw];
    float4 xv = *(const float4*)(xr + k);
    acc += xv.x * w0 + xv.y * w1 + xv.z * w2 + xv.w * w3;
  }
  return acc;
}

// attention over 256 keys for one (b,h); KT [d][n], V [n][512]
__device__ __forceinline__ void attn_unit(
    const float* __restrict__ qrow, int h,
    const float* __restrict__ KT, const float* __restrict__ V,
    float* __restrict__ outrow,
    float* sQh, float* sP, float* sB, float* redM, float* redS, int tid) {
  int w = tid >> 6, lane = tid & 63;
  if (tid < DH) sQh[tid] = qrow[h * DH + tid];
  __syncthreads();
  const float* kp = KT + (size_t)(h * DH) * NN + tid;
  float a = 0.f;
  #pragma unroll 8
  for (int i = 0; i < DH; i++) a += sQh[i] * kp[(size_t)i * NN];
  a *= 0.125f;
  float m = a;
  #pragma unroll
  for (int s = 32; s >= 1; s >>= 1) m = fmaxf(m, __shfl_xor(m, s));
  if (lane == 0) redM[w] = m;
  __syncthreads();
  m = fmaxf(fmaxf(redM[0], redM[1]), fmaxf(redM[2], redM[3]));
  float e = __expf(a - m);
  float ss = e;
  #pragma unroll
  for (int s = 32; s >= 1; s >>= 1) ss += __shfl_xor(ss, s);
  if (lane == 0) redS[w] = ss;
  sP[tid] = e;
  __syncthreads();
  float inv = 1.f / (redS[0] + redS[1] + redS[2] + redS[3]);
  int q4 = tid >> 6, d = tid & 63;
  const float* vp = V + (size_t)(q4 * 64) * DD + h * DH + d;
  float acc = 0.f;
  #pragma unroll 4
  for (int n = 0; n < 64; n++) acc += sP[q4 * 64 + n] * vp[(size_t)n * DD];
  sB[tid] = acc;
  __syncthreads();
  if (tid < 64)
    outrow[h * DH + tid] = (sB[tid] + sB[64 + tid] + sB[128 + tid] + sB[192 + tid]) * inv;
  __syncthreads();
}

// ---- the persistent decode kernel ------------------------------------------
__global__ __launch_bounds__(256) void decode_persistent(Params P) {
  __shared__ __align__(16) float sX[4 * DD];   // 8 KB staging
  __shared__ float sAux[128];
  int tid = threadIdx.x;
  int bid = blockIdx.x;
  unsigned round = 0;

  float* lm   = sAux;        // 8
  float* li   = sAux + 8;    // 8
  float* red  = sAux + 16;   // 24
  float* redM = sAux + 16;   // 4
  float* redS = sAux + 24;   // 4
  float* sInv = sAux + 40;   // 8
  float* sQh  = sAux + 48;   // 64

  for (int t = 0; t < TT; t++) {
    // ---- Phase A: proj4 (qsa, Ksa[t], Vsa[t], qs) --------------------------
    {
      int m = bid >> 6, jb = (bid >> 3) & 7, bg = bid & 7;
      stage4(sX, P.xcur + (size_t)(bg * 4) * DD, tid);
      __syncthreads();
      const int wmap[4] = {0, 1, 2, 6};
      int col = jb * 64 + (tid & 63);
      int b = bg * 4 + (tid >> 6);
      const float* wp = P.wt8 + (size_t)wmap[m] * DD * DD + col;
      float acc = gemv1(sX, wp, DD, tid);
      if (m == 0)      P.qsa[(size_t)b * DD + col] = acc + P.sa_bq[col];
      else if (m == 1) P.Ksa[((size_t)b * TT + t) * DD + col] = acc + P.sa_bk[col];
      else if (m == 2) P.Vsa[((size_t)b * TT + t) * DD + col] = acc + P.sa_bv[col];
      else             P.qs[(size_t)b * DD + col] = acc + P.s_bq[col];
    }
    gsync(P.flags, P.rel, round, tid, bid);

    // ---- Phase B: self-attn (32 blocks) + spatial attn (224 blocks) --------
    if (bid < NB) {
      int b = bid, L = t + 1;
      float* sQ = sX; float* sP = sX + DD;
      sQ[tid] = P.qsa[(size_t)b * DD + tid];
      sQ[tid + 256] = P.qsa[(size_t)b * DD + tid + 256];
      __syncthreads();
      for (int p = tid; p < NH * L; p += 256) {
        int h = p / L, j = p - h * L;
        const float* kp = P.Ksa + ((size_t)b * TT + j) * DD + h * DH;
        const float* qp = sQ + h * DH;
        float a = 0.f;
        #pragma unroll
        for (int i = 0; i < DH; i += 4) {
          float4 kv = *(const float4*)(kp + i);
          a += qp[i] * kv.x + qp[i + 1] * kv.y + qp[i + 2] * kv.z + qp[i + 3] * kv.w;
        }
        sP[h * 64 + j] = a * 0.125f;
      }
      __syncthreads();
      if (tid < NH) {
        float mx = -1e30f;
        for (int j = 0; j < L; j++) mx = fmaxf(mx, sP[tid * 64 + j]);
        float s = 0.f;
        for (int j = 0; j < L; j++) {
          float e = __expf(sP[tid * 64 + j] - mx);
          sP[tid * 64 + j] = e;
          s += e;
        }
        sInv[tid] = 1.f / s;
      }
      __syncthreads();
      for (int d = tid; d < DD; d += 256) {
        int h = d >> 6;
        const float* vp = P.Vsa + (size_t)b * TT * DD + d;
        float a = 0.f;
        for (int j = 0; j < L; j++) a += sP[h * 64 + j] * vp[(size_t)j * DD];
        P.aSA[(size_t)b * DD + d] = a * sInv[h];
      }
    } else {
      for (int u = bid - NB; u < NB * NH; u += NBLK - NB) {
        int b = u >> 3, h = u & 7;
        attn_unit(P.qs + (size_t)b * DD, h, P.KsT + (size_t)b * NN * DD,
                  P.Vs + (size_t)b * NN * DD, P.aSP + (size_t)b * DD,
                  sQh, sX + DD, sX + 2 * DD, redM, redS, tid);
      }
    }
    gsync(P.flags, P.rel, round, tid, bid);

    // ---- Phase C: u1 = aSA@saWo + sa_bo + x ; ctx = aSP@sWo + s_bo ---------
    if (bid < 128) {
      int mz = bid >> 6, jb = (bid >> 3) & 7, bg = bid & 7;
      const float* src = (mz ? P.aSP : P.aSA) + (size_t)(bg * 4) * DD;
      stage4(sX, src, tid);
      __syncthreads();
      int col = jb * 64 + (tid & 63);
      int b = bg * 4 + (tid >> 6);
      const float* wp = P.wt8 + (size_t)(mz ? 7 : 3) * DD * DD + col;
      float acc = gemv1(sX, wp, DD, tid);
      if (mz == 0)
        P.u1[(size_t)b * DD + col] = acc + P.sa_bo[col] + P.xcur[(size_t)b * DD + col];
      else
        P.ctx[(size_t)b * DD + col] = acc + P.s_bo[col];
    }
    gsync(P.flags, P.rel, round, tid, bid);

    // ---- Phase D: LN1(u1) -> y1 ; qc = y1@caWq + ca_bq ---------------------
    if (bid < 64) {
      int jb = bid >> 3, bg = bid & 7;
      stage4(sX, P.u1 + (size_t)(bg * 4) * DD, tid);
      __syncthreads();
      ln4(sX, P.ln1w, P.ln1b, lm, li, tid);
      if (jb == 0) {
        #pragma unroll
        for (int r = 0; r < 4; r++) {
          P.y1[(size_t)(bg * 4 + r) * DD + tid] = sX[r * DD + tid];
          P.y1[(size_t)(bg * 4 + r) * DD + tid + 256] = sX[r * DD + tid + 256];
        }
      }
      int col = jb * 64 + (tid & 63);
      int b = bg * 4 + (tid >> 6);
      const float* wp = P.wt8 + 4ull * DD * DD + col;
      float acc = gemv1(sX, wp, DD, tid);
      P.qc[(size_t)b * DD + col] = acc + P.ca_bq[col];
    }
    gsync(P.flags, P.rel, round, tid, bid);

    // ---- Phase E: cross-attn, one (b,h) per block --------------------------
    {
      int b = bid >> 3, h = bid & 7;
      attn_unit(P.qc + (size_t)b * DD, h, P.KcT + (size_t)b * NN * DD,
                P.Vc + (size_t)b * NN * DD, P.aCA + (size_t)b * DD,
                sQh, sX + DD, sX + 2 * DD, redM, redS, tid);
    }
    gsync(P.flags, P.rel, round, tid, bid);

    // ---- Phase F: u2 = aCA@caWo + ca_bo + y1 -------------------------------
    if (bid < 64) {
      int jb = bid >> 3, bg = bid & 7;
      stage4(sX, P.aCA + (size_t)(bg * 4) * DD, tid);
      __syncthreads();
      int col = jb * 64 + (tid & 63);
      int b = bg * 4 + (tid >> 6);
      const float* wp = P.wt8 + 5ull * DD * DD + col;
      float acc = gemv1(sX, wp, DD, tid);
      P.u2[(size_t)b * DD + col] = acc + P.ca_bo[col] + P.y1[(size_t)b * DD + col];
    }
    gsync(P.flags, P.rel, round, tid, bid);

    // ---- Phase G: LN2(u2)=z ; u3 = z + b2 (jb==0) ; hbuf = relu(z@W1+b1) ---
    {
      int jb = bid >> 3, bg = bid & 7;  // jb 0..31 (64 cols of 2048)
      stage4(sX, P.u2 + (size_t)(bg * 4) * DD, tid);
      __syncthreads();
      ln4(sX, P.ln2w, P.ln2b, lm, li, tid);
      if (jb == 0) {
        float f0 = P.b2[tid], f1 = P.b2[tid + 256];
        #pragma unroll
        for (int r = 0; r < 4; r++) {
          P.u3[(size_t)(bg * 4 + r) * DD + tid] = sX[r * DD + tid] + f0;
          P.u3[(size_t)(bg * 4 + r) * DD + tid + 256] = sX[r * DD + tid + 256] + f1;
        }
      }
      int col = jb * 64 + (tid & 63);   // [0, 2048)
      int b = bg * 4 + (tid >> 6);
      const float* wp = P.W1t + col;
      float acc = gemv1(sX, wp, DF, tid);
      P.hbuf[(size_t)b * DF + col] = fmaxf(acc + P.b1[col], 0.f);
    }
    gsync(P.flags, P.rel, round, tid, bid);

    // ---- Phase H: u3 += hbuf@W2 (split-k x4, atomic) -----------------------
    {
      int jb = bid & 7, bg = (bid >> 3) & 7, ks = bid >> 6;
      #pragma unroll
      for (int q = 0; q < 2; q++) {
        int f = q * 1024 + tid * 4, r = f >> 9, c = f & 511;
        *(float4*)(sX + f) =
            *(const float4*)(P.hbuf + (size_t)(bg * 4 + r) * DF + ks * 512 + c);
      }
      __syncthreads();
      int col = jb * 64 + (tid & 63);
      int b = bg * 4 + (tid >> 6);
      const float* wp = P.W2t + (size_t)(ks * 512) * DD + col;
      float acc = gemv1(sX, wp, DD, tid);
      atomicAdd(&P.u3[(size_t)b * DD + col], acc);
    }
    gsync(P.flags, P.rel, round, tid, bid);

    // ---- Phase I: nxt = LN3(u3) + ctx ; out ; xcur = nxt + pe[t+1] ---------
    if (bid < NB) {
      int b = bid, wv = tid >> 6, lane = tid & 63;
      float u0 = P.u3[(size_t)b * DD + tid];
      float u1v = P.u3[(size_t)b * DD + tid + 256];
      float s = u0 + u1v, q = u0 * u0 + u1v * u1v;
      #pragma unroll
      for (int m = 32; m >= 1; m >>= 1) { s += __shfl_xor(s, m); q += __shfl_xor(q, m); }
      if (lane == 0) { red[wv] = s; red[8 + wv] = q; }
      __syncthreads();
      if (tid == 0) {
        float ss = red[0] + red[1] + red[2] + red[3];
        float qq = red[8] + red[9] + red[10] + red[11];
        float mm = ss * (1.0f / 512.0f);
        red[16] = mm;
        red[17] = rsqrtf(qq * (1.0f / 512.0f) - mm * mm + 1e-5f);
      }
      __syncthreads();
      float mean = red[16], inv = red[17];
      float n0 = (u0 - mean) * inv * P.ln3w[tid] + P.ln3b[tid] +
                 P.ctx[(size_t)b * DD + tid];
      float n1 = (u1v - mean) * inv * P.ln3w[tid + 256] + P.ln3b[tid + 256] +
                 P.ctx[(size_t)b * DD + tid + 256];
      sX[tid] = n0; sX[tid + 256] = n1;
      float p0 = (t < TT - 1) ? P.pe[(size_t)(t + 1) * DD + tid] : 0.f;
      float p1 = (t < TT - 1) ? P.pe[(size_t)(t + 1) * DD + tid + 256] : 0.f;
      P.xcur[(size_t)b * DD + tid] = n0 + p0;
      P.xcur[(size_t)b * DD + tid + 256] = n1 + p1;
      __syncthreads();
      int c = tid >> 7, l = tid & 127;
      float a = 0.f;
      #pragma unroll
      for (int i = 0; i < 4; i++) a += sX[l + i * 128] * P.Wout[(size_t)c * DD + l + i * 128];
      #pragma unroll
      for (int m = 32; m >= 1; m >>= 1) a += __shfl_xor(a, m);
      if ((tid & 63) == 0) red[tid >> 6] = a;
      __syncthreads();
      if (tid == 0)   P.out[((size_t)b * TT + t) * 2 + 0] = red[0] + red[1] + P.bout[0];
      if (tid == 128) P.out[((size_t)b * TT + t) * 2 + 1] = red[2] + red[3] + P.bout[1];
    }
    gsync(P.flags, P.rel, round, tid, bid);
  }
}

// ---- precompute kernels -----------------------------------------------------
struct TPItem { const float* in; float* out; int R; int C; };
struct TPArgs { TPItem m[10]; };

__global__ __launch_bounds__(256) void transpose_many(TPArgs args) {
  const TPItem t = args.m[blockIdx.z];
  int r0 = blockIdx.x * 32, c0 = blockIdx.y * 32;
  if (r0 >= t.R || c0 >= t.C) return;
  __shared__ float tile[32][33];
  int tid = threadIdx.x;
  int i = tid >> 3, j4 = (tid & 7) * 4;
  float4 v = *(const float4*)(t.in + (size_t)(r0 + i) * t.C + c0 + j4);
  tile[i][j4] = v.x; tile[i][j4 + 1] = v.y; tile[i][j4 + 2] = v.z; tile[i][j4 + 3] = v.w;
  __syncthreads();
  float4 o;
  o.x = tile[j4][i]; o.y = tile[j4 + 1][i]; o.z = tile[j4 + 2][i]; o.w = tile[j4 + 3][i];
  *(float4*)(t.out + (size_t)(c0 + i) * t.R + r0 + j4) = o;
}

__global__ __launch_bounds__(256) void transpose_kv(const float* __restrict__ Ks,
                                                    const float* __restrict__ Kc,
                                                    float* __restrict__ KsT,
                                                    float* __restrict__ KcT) {
  int z = blockIdx.z;
  int b = z >> 1;
  const float* in = ((z & 1) ? Kc : Ks) + (size_t)b * NN * DD;
  float* out = ((z & 1) ? KcT : KsT) + (size_t)b * NN * DD;
  int r0 = blockIdx.x * 32, c0 = blockIdx.y * 32;
  __shared__ float tile[32][33];
  int tid = threadIdx.x;
  int i = tid >> 3, j4 = (tid & 7) * 4;
  float4 v = *(const float4*)(in + (size_t)(r0 + i) * DD + c0 + j4);
  tile[i][j4] = v.x; tile[i][j4 + 1] = v.y; tile[i][j4 + 2] = v.z; tile[i][j4 + 3] = v.w;
  __syncthreads();
  float4 o;
  o.x = tile[j4][i]; o.y = tile[j4 + 1][i]; o.z = tile[j4 + 2][i]; o.w = tile[j4 + 3][i];
  *(float4*)(out + (size_t)(c0 + i) * NN + r0 + j4) = o;
}

__global__ __launch_bounds__(256) void init_x(const float* __restrict__ hv0,
                                              const float* __restrict__ pe,
                                              float* __restrict__ xcur,
                                              unsigned* __restrict__ flags) {
  int i = blockIdx.x * 256 + threadIdx.x;
  xcur[i] = hv0[i] + pe[i & (DD - 1)];
  if (i < NBLK * FLAG_STRIDE + 32) flags[i] = 0u;  // flags + rel line
}

__global__ __launch_bounds__(256) void gemm_kv(
    const float* __restrict__ A,
    const float* __restrict__ W0, const float* __restrict__ W1_,
    const float* __restrict__ W2_, const float* __restrict__ W3_,
    const float* __restrict__ b0, const float* __restrict__ b1_,
    const float* __restrict__ b2_, const float* __restrict__ b3_,
    float* __restrict__ O0, float* __restrict__ O1,
    float* __restrict__ O2, float* __restrict__ O3) {
  __shared__ __align__(16) float As[8][128];
  __shared__ __align__(16) float Bs[8][128];
  int tid = threadIdx.x;
  int bx = blockIdx.x, by = blockIdx.y;
  int mm = bx >> 2;
  int col0 = (bx & 3) * 128;
  const float* W = mm == 0 ? W0 : mm == 1 ? W1_ : mm == 2 ? W2_ : W3_;
  const float* bias = mm == 0 ? b0 : mm == 1 ? b1_ : mm == 2 ? b2_ : b3_;
  float* O = mm == 0 ? O0 : mm == 1 ? O1 : mm == 2 ? O2 : O3;
  int tx = tid & 15, ty = tid >> 4;
  int m0 = by * 128;
  int lr = tid >> 1, lk = (tid & 1) * 4;
  const float* Ap = A + (size_t)(m0 + lr) * DD + lk;
  const float* Wp = W + (size_t)(col0 + lr) * DD + lk;
  float c[8][8] = {};
  for (int k0 = 0; k0 < DD; k0 += 8) {
    float4 av = *(const float4*)(Ap + k0);
    float4 wv = *(const float4*)(Wp + k0);
    __syncthreads();
    As[lk + 0][lr] = av.x; As[lk + 1][lr] = av.y; As[lk + 2][lr] = av.z; As[lk + 3][lr] = av.w;
    Bs[lk + 0][lr] = wv.x; Bs[lk + 1][lr] = wv.y; Bs[lk + 2][lr] = wv.z; Bs[lk + 3][lr] = wv.w;
    __syncthreads();
    #pragma unroll
    for (int k = 0; k < 8; k++) {
      float a[8], bb[8];
      *(float4*)&a[0] = *(const float4*)&As[k][ty * 8];
      *(float4*)&a[4] = *(const float4*)&As[k][ty * 8 + 4];
      *(float4*)&bb[0] = *(const float4*)&Bs[k][tx * 8];
      *(float4*)&bb[4] = *(const float4*)&Bs[k][tx * 8 + 4];
      #pragma unroll
      for (int i = 0; i < 8; i++)
        #pragma unroll
        for (int j = 0; j < 8; j++) c[i][j] += a[i] * bb[j];
    }
  }
  const float* bp = bias + col0 + tx * 8;
  for (int i = 0; i < 8; i++) {
    int row = m0 + ty * 8 + i;
    float* op = O + (size_t)row * DD + col0 + tx * 8;
    #pragma unroll
    for (int jq = 0; jq < 8; jq += 4) {
      float4 v;
      v.x = c[i][jq + 0] + bp[jq + 0];
      v.y = c[i][jq + 1] + bp[jq + 1];
      v.z = c[i][jq + 2] + bp[jq + 2];
      v.w = c[i][jq + 3] + bp[jq + 3];
      *(float4*)(op + jq) = v;
    }
  }
}

// ---------------------------------------------------------------------------
extern "C" void kernel_launch(void* const* d_in, const int* in_sizes, int n_in,
                              void* d_out, int out_size, void* d_ws, size_t ws_size,
                              hipStream_t stream) {
  const float* H_v_all = (const float*)d_in[0];
  const float* H_v0    = (const float*)d_in[1];
  const float* pe      = (const float*)d_in[2];
  const float* s_Wq = (const float*)d_in[3];
  const float* s_Wk = (const float*)d_in[4];
  const float* s_Wv = (const float*)d_in[5];
  const float* s_Wo = (const float*)d_in[6];
  const float* s_bq = (const float*)d_in[7];
  const float* s_bk = (const float*)d_in[8];
  const float* s_bv = (const float*)d_in[9];
  const float* s_bo = (const float*)d_in[10];
  const float* sa_Wq = (const float*)d_in[11];
  const float* sa_Wk = (const float*)d_in[12];
  const float* sa_Wv = (const float*)d_in[13];
  const float* sa_Wo = (const float*)d_in[14];
  const float* sa_bq = (const float*)d_in[15];
  const float* sa_bk = (const float*)d_in[16];
  const float* sa_bv = (const float*)d_in[17];
  const float* sa_bo = (const float*)d_in[18];
  const float* ca_Wq = (const float*)d_in[19];
  const float* ca_Wk = (const float*)d_in[20];
  const float* ca_Wv = (const float*)d_in[21];
  const float* ca_Wo = (const float*)d_in[22];
  const float* ca_bq = (const float*)d_in[23];
  const float* ca_bk = (const float*)d_in[24];
  const float* ca_bv = (const float*)d_in[25];
  const float* ca_bo = (const float*)d_in[26];
  const float* ln1w = (const float*)d_in[27];
  const float* ln1b = (const float*)d_in[28];
  const float* ln2w = (const float*)d_in[29];
  const float* ln2b = (const float*)d_in[30];
  const float* ln3w = (const float*)d_in[31];
  const float* ln3b = (const float*)d_in[32];
  const float* W1   = (const float*)d_in[33];
  const float* b1   = (const float*)d_in[34];
  const float* W2   = (const float*)d_in[35];
  const float* b2   = (const float*)d_in[36];
  const float* Wout = (const float*)d_in[37];
  const float* bout = (const float*)d_in[38];

  float* ws  = (float*)d_ws;
  float* Ks  = ws + OFF_KS;
  float* Vs  = ws + OFF_VS;
  float* Kc  = ws + OFF_KC;
  float* Vc  = ws + OFF_VC;
  float* KsT = ws + OFF_KST;
  float* KcT = ws + OFF_KCT;
  float* Ksa = ws + OFF_KSA;
  float* Vsa = ws + OFF_VSA;
  float* wt8 = ws + OFF_WT;
  float* W1t = ws + OFF_W1T;
  float* W2t = ws + OFF_W2T;
  float* xcur = ws + OFF_X;
  unsigned* flags = (unsigned*)(ws + OFF_FLG);

  // --- precompute -----------------------------------------------------------
  TPArgs tp;
  tp.m[0] = {sa_Wq, wt8 + 0ull * DD * DD, DD, DD};
  tp.m[1] = {sa_Wk, wt8 + 1ull * DD * DD, DD, DD};
  tp.m[2] = {sa_Wv, wt8 + 2ull * DD * DD, DD, DD};
  tp.m[3] = {sa_Wo, wt8 + 3ull * DD * DD, DD, DD};
  tp.m[4] = {ca_Wq, wt8 + 4ull * DD * DD, DD, DD};
  tp.m[5] = {ca_Wo, wt8 + 5ull * DD * DD, DD, DD};
  tp.m[6] = {s_Wq,  wt8 + 6ull * DD * DD, DD, DD};
  tp.m[7] = {s_Wo,  wt8 + 7ull * DD * DD, DD, DD};
  tp.m[8] = {W1, W1t, DF, DD};
  tp.m[9] = {W2, W2t, DD, DF};
  hipLaunchKernelGGL(transpose_many, dim3(64, 64, 10), dim3(256), 0, stream, tp);

  hipLaunchKernelGGL(gemm_kv, dim3(16, 64), dim3(256), 0, stream,
                     H_v_all, s_Wk, s_Wv, ca_Wk, ca_Wv,
                     s_bk, s_bv, ca_bk, ca_bv, Ks, Vs, Kc, Vc);

  hipLaunchKernelGGL(transpose_kv, dim3(8, 16, 64), dim3(256), 0, stream,
                     Ks, Kc, KsT, KcT);

  hipLaunchKernelGGL(init_x, dim3(64), dim3(256), 0, stream, H_v0, pe, xcur, flags);

  // --- one persistent kernel for all 60 steps -------------------------------
  Params P;
  P.pe = pe;
  P.sa_bq = sa_bq; P.sa_bk = sa_bk; P.sa_bv = sa_bv; P.sa_bo = sa_bo;
  P.s_bq = s_bq; P.s_bo = s_bo; P.ca_bq = ca_bq; P.ca_bo = ca_bo;
  P.ln1w = ln1w; P.ln1b = ln1b; P.ln2w = ln2w; P.ln2b = ln2b;
  P.ln3w = ln3w; P.ln3b = ln3b;
  P.b1 = b1; P.b2 = b2; P.Wout = Wout; P.bout = bout;
  P.wt8 = wt8; P.W1t = W1t; P.W2t = W2t;
  P.KsT = KsT; P.KcT = KcT; P.Vs = Vs; P.Vc = Vc;
  P.Ksa = Ksa; P.Vsa = Vsa; P.xcur = xcur;
  P.qsa = ws + OFF_QSA; P.qs = ws + OFF_QS;
  P.aSA = ws + OFF_ASA; P.aSP = ws + OFF_ASP; P.aCA = ws + OFF_ACA;
  P.u1 = ws + OFF_U1; P.y1 = ws + OFF_Y1; P.qc = ws + OFF_QC;
  P.u2 = ws + OFF_U2; P.ctx = ws + OFF_CTX; P.u3 = ws + OFF_U3;
  P.hbuf = ws + OFF_H;
  P.out = (float*)d_out;
  P.flags = flags;
  P.rel = flags + (size_t)NBLK * FLAG_STRIDE;

  void* kargs[] = { (void*)&P };
  hipLaunchCooperativeKernel((void*)decode_persistent, dim3(NBLK), dim3(256),
                             kargs, 0, stream);
}

// Round 5
// 8066.187 us; speedup vs baseline: 3.5347x; 1.5294x over previous
//
#include <hip/hip_runtime.h>

// ---------------------------------------------------------------------------
// VehicleTrajectoryDecoder: B=32, N=256, D=512, H=8 (dh=64), T=60, DFF=2048.
// R5: R4 counters (VALUBusy 5%, 88MB/step refetch, 11.9ms = bytes/460GB/s)
// showed the agent-scope __threadfence in the grid barrier does an L2
// writeback+invalidate per block per phase -> every step re-fetches all
// weights/KV. Fix: mutable cross-block buffers use relaxed agent-scope
// atomics (sc1, MALL-coherent, bypass L2); barrier = waitcnt + relaxed flags
// (no fences); weights/KV stay warm in L2. Spatial/cross K/V cast to bf16
// (halves the 64MB/step stream; fits per-XCD L2 with head-pinned blocks).
// ---------------------------------------------------------------------------

#define NB 32
#define NN 256
#define DD 512
#define NH 8
#define DH 64
#define TT 60
#define DF 2048
#define NBLK 256
#define FLAG_STRIDE 32   // 128B per flag line

typedef unsigned short ushort_t;

// ---- workspace layout (float element offsets) ------------------------------
constexpr size_t SZ_KV  = (size_t)NB * NN * DD;     // 4194304
constexpr size_t SZ_SA  = (size_t)NB * TT * DD;     // 983040
constexpr size_t SZ_ROW = (size_t)NB * DD;          // 16384
// precompute-only fp32 scratch (dead before decode starts):
constexpr size_t OFF_KS32 = 0;
constexpr size_t OFF_VS32 = SZ_KV;
constexpr size_t OFF_KC32 = 2 * SZ_KV;
constexpr size_t OFF_VC32 = 3 * SZ_KV;
// decode-time overlay of the scratch region:
constexpr size_t OFF_KSA = 0;                 // fp32 [b][t][d]
constexpr size_t OFF_VSA = SZ_SA;
constexpr size_t OFF_ACT = 2 * SZ_SA;
constexpr size_t OFF_X   = OFF_ACT;
constexpr size_t OFF_QSA = OFF_X   + SZ_ROW;
constexpr size_t OFF_QS  = OFF_QSA + SZ_ROW;
constexpr size_t OFF_ASA = OFF_QS  + SZ_ROW;
constexpr size_t OFF_ASP = OFF_ASA + SZ_ROW;
constexpr size_t OFF_ACA = OFF_ASP + SZ_ROW;
constexpr size_t OFF_U1  = OFF_ACA + SZ_ROW;
constexpr size_t OFF_Y1  = OFF_U1  + SZ_ROW;
constexpr size_t OFF_QC  = OFF_Y1  + SZ_ROW;
constexpr size_t OFF_U2  = OFF_QC  + SZ_ROW;
constexpr size_t OFF_CTX = OFF_U2  + SZ_ROW;
constexpr size_t OFF_U3  = OFF_CTX + SZ_ROW;
constexpr size_t OFF_H   = OFF_U3  + SZ_ROW;  // hbuf [32][2048]
// bf16 K/V (ushort) base, after the 64MB scratch:
constexpr size_t OFF_BF  = 4 * SZ_KV;         // floats; cast to ushort*
// ushort offsets inside BF region:
constexpr size_t UOFF_KST = 0;                // KsT bf16 [b][d][n]
constexpr size_t UOFF_KCT = SZ_KV;            // KcT bf16 [b][d][n]
constexpr size_t UOFF_VS  = 2 * SZ_KV;        // Vs  bf16 [b][n][d]
constexpr size_t UOFF_VC  = 3 * SZ_KV;        // Vc  bf16 [b][n][d]
constexpr size_t OFF_WT  = OFF_BF + 2 * SZ_KV;        // 8 transposed 512x512 fp32
constexpr size_t OFF_W1T = OFF_WT  + 8ull * DD * DD;  // [512][2048]
constexpr size_t OFF_W2T = OFF_W1T + (size_t)DD * DF; // [2048][512]
constexpr size_t OFF_FLG = OFF_W2T + (size_t)DF * DD; // flags + rel
// total ~117.5 MB

// ---- sc1 (agent-scope, MALL-coherent) access helpers ------------------------
__device__ __forceinline__ float ldg_a(const float* p) {
  return __hip_atomic_load(p, __ATOMIC_RELAXED, __HIP_MEMORY_SCOPE_AGENT);
}
__device__ __forceinline__ void stg_a(float* p, float v) {
  __hip_atomic_store(p, v, __ATOMIC_RELAXED, __HIP_MEMORY_SCOPE_AGENT);
}
__device__ __forceinline__ float bf2f(ushort_t u) {
  return __uint_as_float(((unsigned)u) << 16);
}
__device__ __forceinline__ ushort_t f2bf(float f) {
  unsigned u = __float_as_uint(f);
  return (ushort_t)((u + 0x7FFFu + ((u >> 16) & 1u)) >> 16);
}

// ---- params ----------------------------------------------------------------
struct Params {
  const float *pe;
  const float *sa_bq, *sa_bk, *sa_bv, *sa_bo;
  const float *s_bq, *s_bo, *ca_bq, *ca_bo;
  const float *ln1w, *ln1b, *ln2w, *ln2b, *ln3w, *ln3b;
  const float *b1, *b2, *Wout, *bout;
  const float *wt8, *W1t, *W2t;
  const ushort_t *KsTb, *KcTb, *VsB, *VcB;
  float *Ksa, *Vsa, *xcur, *qsa, *qs, *aSA, *aSP, *aCA;
  float *u1, *y1, *qc, *u2, *ctx, *u3, *hbuf;
  float *out;
  unsigned *flags, *rel;
};

// ---- grid barrier: no fences; data moves via sc1, flags via relaxed atomics.
__device__ __forceinline__ void gsync(unsigned* flags, unsigned* rel,
                                      unsigned& round, int tid, int bid) {
  __builtin_amdgcn_s_waitcnt(0);   // each wave drains its own vmem ops
  __syncthreads();
  round++;
  if (bid == 0) {
    if (tid > 0 && tid < NBLK) {
      while (__hip_atomic_load(&flags[(size_t)tid * FLAG_STRIDE],
                               __ATOMIC_RELAXED, __HIP_MEMORY_SCOPE_AGENT) < round)
        __builtin_amdgcn_s_sleep(1);
    }
    __syncthreads();
    if (tid == 0)
      __hip_atomic_store(rel, round, __ATOMIC_RELAXED, __HIP_MEMORY_SCOPE_AGENT);
  } else {
    if (tid == 0) {
      __hip_atomic_store(&flags[(size_t)bid * FLAG_STRIDE], round,
                         __ATOMIC_RELAXED, __HIP_MEMORY_SCOPE_AGENT);
      while (__hip_atomic_load(rel, __ATOMIC_RELAXED,
                               __HIP_MEMORY_SCOPE_AGENT) < round)
        __builtin_amdgcn_s_sleep(1);
    }
  }
  __syncthreads();
}

// stage 4 rows of 512 floats from a mutable buffer (sc1 scalar loads)
__device__ __forceinline__ void stage4a(float* sX, const float* src, int tid) {
  #pragma unroll
  for (int q = 0; q < 8; q++) sX[q * 256 + tid] = ldg_a(src + q * 256 + tid);
}

// in-place LayerNorm of 4 LDS rows (wave w handles row w)
__device__ __forceinline__ void ln4(float* sX, const float* w, const float* b,
                                    float* lm, float* li, int tid) {
  int wv = tid >> 6, lane = tid & 63;
  float s = 0.f, q = 0.f;
  #pragma unroll
  for (int i = 0; i < 8; i++) {
    float v = sX[wv * DD + lane + i * 64];
    s += v; q += v * v;
  }
  #pragma unroll
  for (int m = 32; m >= 1; m >>= 1) { s += __shfl_xor(s, m); q += __shfl_xor(q, m); }
  if (lane == 0) {
    float mm = s * (1.0f / 512.0f);
    lm[wv] = mm;
    li[wv] = rsqrtf(q * (1.0f / 512.0f) - mm * mm + 1e-5f);
  }
  __syncthreads();
  float w0 = w[tid], w1 = w[tid + 256], b0 = b[tid], b1 = b[tid + 256];
  #pragma unroll
  for (int r = 0; r < 4; r++) {
    sX[r * DD + tid]       = (sX[r * DD + tid]       - lm[r]) * li[r] * w0 + b0;
    sX[r * DD + tid + 256] = (sX[r * DD + tid + 256] - lm[r]) * li[r] * w1 + b1;
  }
  __syncthreads();
}

// GEMV: 1 output/thread; 4 rows in sX; weight column-major [k][col] cached
__device__ __forceinline__ float gemv1(const float* sX, const float* wp,
                                       int ldw, int tid) {
  const float* xr = sX + (tid >> 6) * DD;
  float acc = 0.f;
  for (int k = 0; k < DD; k += 4) {
    float w0 = wp[(size_t)(k + 0) * ldw];
    float w1 = wp[(size_t)(k + 1) * ldw];
    float w2 = wp[(size_t)(k + 2) * ldw];
    float w3 = wp[(size_t)(k + 3) * ldw];
    float4 xv = *(const float4*)(xr + k);
    acc += xv.x * w0 + xv.y * w1 + xv.z * w2 + xv.w * w3;
  }
  return acc;
}

// attention over 256 keys for one (b,h), bf16 KT [d][n] / V [n][512]
__device__ __forceinline__ void attn256_bf16(
    const float* __restrict__ qbuf, int b, int h,
    const ushort_t* __restrict__ KTb, const ushort_t* __restrict__ Vb,
    float* __restrict__ outrow,
    float* sQh, float* sP, float* sB, float* redM, float* redS, int tid) {
  int w = tid >> 6, lane = tid & 63;
  if (tid < DH) sQh[tid] = ldg_a(qbuf + (size_t)b * DD + h * DH + tid);
  __syncthreads();
  const ushort_t* kp = KTb + (size_t)b * DD * NN + (size_t)(h * DH) * NN + tid;
  float a = 0.f;
  #pragma unroll 8
  for (int i = 0; i < DH; i++) a += sQh[i] * bf2f(kp[(size_t)i * NN]);
  a *= 0.125f;
  float m = a;
  #pragma unroll
  for (int s = 32; s >= 1; s >>= 1) m = fmaxf(m, __shfl_xor(m, s));
  if (lane == 0) redM[w] = m;
  __syncthreads();
  m = fmaxf(fmaxf(redM[0], redM[1]), fmaxf(redM[2], redM[3]));
  float e = __expf(a - m);
  float ss = e;
  #pragma unroll
  for (int s = 32; s >= 1; s >>= 1) ss += __shfl_xor(ss, s);
  if (lane == 0) redS[w] = ss;
  sP[tid] = e;
  __syncthreads();
  float inv = 1.f / (redS[0] + redS[1] + redS[2] + redS[3]);
  int g = tid >> 6, d = tid & 63;
  const ushort_t* vp = Vb + (size_t)b * NN * DD + (size_t)(g * 64) * DD + h * DH + d;
  float acc = 0.f;
  #pragma unroll 4
  for (int n = 0; n < 64; n++) acc += sP[g * 64 + n] * bf2f(vp[(size_t)n * DD]);
  sB[tid] = acc;
  __syncthreads();
  if (tid < 64)
    stg_a(outrow + h * DH + tid,
          (sB[tid] + sB[64 + tid] + sB[128 + tid] + sB[192 + tid]) * inv);
  __syncthreads();
}

// ---- persistent decode ------------------------------------------------------
__global__ __launch_bounds__(256) void decode_persistent(Params P) {
  __shared__ __align__(16) float sX[4 * DD];
  __shared__ float sAux[128];
  int tid = threadIdx.x;
  int bid = blockIdx.x;
  unsigned round = 0;

  float* lm   = sAux;
  float* li   = sAux + 8;
  float* red  = sAux + 16;   // 24
  float* redM = sAux + 16;
  float* redS = sAux + 24;
  float* sInv = sAux + 40;
  float* sQh  = sAux + 48;   // 64

  for (int t = 0; t < TT; t++) {
    // ---- Phase A: proj4. cs=bid&31 (XCD-pinned weight slice), bg=bid>>5 ----
    {
      int cs = bid & 31, bg = bid >> 5;
      int m = cs >> 3, jb = cs & 7;
      stage4a(sX, P.xcur + (size_t)(bg * 4) * DD, tid);
      __syncthreads();
      int col = jb * 64 + (tid & 63);
      int b = bg * 4 + (tid >> 6);
      const float* wp = P.wt8 + (size_t)m * DD * DD + col;  // 0:saWq 1:saWk 2:saWv 3:sWq
      float acc = gemv1(sX, wp, DD, tid);
      if (m == 0)      stg_a(&P.qsa[(size_t)b * DD + col], acc + P.sa_bq[col]);
      else if (m == 1) stg_a(&P.Ksa[((size_t)b * TT + t) * DD + col], acc + P.sa_bk[col]);
      else if (m == 2) stg_a(&P.Vsa[((size_t)b * TT + t) * DD + col], acc + P.sa_bv[col]);
      else             stg_a(&P.qs[(size_t)b * DD + col], acc + P.s_bq[col]);
    }
    gsync(P.flags, P.rel, round, tid, bid);

    // ---- Phase B: spatial attn (b,h) + self-attn (b,h). h=bid&7 (XCD pin) --
    {
      int b = bid >> 3, h = bid & 7;
      float* sP = sX + DD;
      float* sB = sX + 2 * DD;
      attn256_bf16(P.qs, b, h, P.KsTb, P.VsB, P.aSP + (size_t)b * DD,
                   sQh, sP, sB, redM, redS, tid);
      // self-attn, head h over L keys (fp32 cache, immutable rows)
      int L = t + 1;
      if (tid < DH) sQh[tid] = ldg_a(P.qsa + (size_t)b * DD + h * DH + tid);
      __syncthreads();
      float sc = -1e30f;
      if (tid < L) {
        const float* kp = P.Ksa + ((size_t)b * TT + tid) * DD + h * DH;
        float a = 0.f;
        #pragma unroll
        for (int i = 0; i < DH; i += 4) {
          float4 kv = *(const float4*)(kp + i);
          a += sQh[i] * kv.x + sQh[i + 1] * kv.y + sQh[i + 2] * kv.z + sQh[i + 3] * kv.w;
        }
        sc = a * 0.125f;
      }
      if (tid < 64) sP[tid] = sc;
      __syncthreads();
      if (tid < 64) {
        float v = sP[tid];
        float m = v;
        #pragma unroll
        for (int s = 32; s >= 1; s >>= 1) m = fmaxf(m, __shfl_xor(m, s));
        float e = (tid < L) ? __expf(v - m) : 0.f;
        float s2 = e;
        #pragma unroll
        for (int s = 32; s >= 1; s >>= 1) s2 += __shfl_xor(s2, s);
        sP[tid] = e;
        if (tid == 0) sInv[0] = 1.f / s2;
      }
      __syncthreads();
      int g = tid >> 6, d = tid & 63;
      float acc = 0.f;
      for (int j = g; j < L; j += 4)
        acc += sP[j] * P.Vsa[((size_t)b * TT + j) * DD + h * DH + d];
      sB[tid] = acc;
      __syncthreads();
      if (tid < 64)
        stg_a(P.aSA + (size_t)b * DD + h * DH + tid,
              (sB[tid] + sB[64 + tid] + sB[128 + tid] + sB[192 + tid]) * sInv[0]);
    }
    gsync(P.flags, P.rel, round, tid, bid);

    // ---- Phase C: u1 = aSA@saWo + sa_bo + x ; ctx = aSP@sWo + s_bo ---------
    if (bid < 128) {
      int cs = bid & 15, bg = bid >> 4;
      int mz = cs >> 3, jb = cs & 7;
      stage4a(sX, (mz ? P.aSP : P.aSA) + (size_t)(bg * 4) * DD, tid);
      __syncthreads();
      int col = jb * 64 + (tid & 63);
      int b = bg * 4 + (tid >> 6);
      const float* wp = P.wt8 + (size_t)(4 + mz) * DD * DD + col;  // 4:saWo 5:sWo
      float acc = gemv1(sX, wp, DD, tid);
      if (mz == 0)
        stg_a(&P.u1[(size_t)b * DD + col],
              acc + P.sa_bo[col] + ldg_a(&P.xcur[(size_t)b * DD + col]));
      else
        stg_a(&P.ctx[(size_t)b * DD + col], acc + P.s_bo[col]);
    }
    gsync(P.flags, P.rel, round, tid, bid);

    // ---- Phase D: LN1(u1) -> y1 (cs==0) ; qc = y1@caWq + ca_bq -------------
    if (bid < 64) {
      int cs = bid & 7, bg = bid >> 3;
      stage4a(sX, P.u1 + (size_t)(bg * 4) * DD, tid);
      __syncthreads();
      ln4(sX, P.ln1w, P.ln1b, lm, li, tid);
      if (cs == 0) {
        #pragma unroll
        for (int r = 0; r < 4; r++) {
          stg_a(&P.y1[(size_t)(bg * 4 + r) * DD + tid], sX[r * DD + tid]);
          stg_a(&P.y1[(size_t)(bg * 4 + r) * DD + tid + 256], sX[r * DD + tid + 256]);
        }
      }
      int col = cs * 64 + (tid & 63);
      int b = bg * 4 + (tid >> 6);
      const float* wp = P.wt8 + 6ull * DD * DD + col;  // 6:caWq
      float acc = gemv1(sX, wp, DD, tid);
      stg_a(&P.qc[(size_t)b * DD + col], acc + P.ca_bq[col]);
    }
    gsync(P.flags, P.rel, round, tid, bid);

    // ---- Phase E: cross-attn (b,h), h=bid&7 --------------------------------
    {
      int b = bid >> 3, h = bid & 7;
      attn256_bf16(P.qc, b, h, P.KcTb, P.VcB, P.aCA + (size_t)b * DD,
                   sQh, sX + DD, sX + 2 * DD, redM, redS, tid);
    }
    gsync(P.flags, P.rel, round, tid, bid);

    // ---- Phase F: u2 = aCA@caWo + ca_bo + y1 -------------------------------
    if (bid < 64) {
      int cs = bid & 7, bg = bid >> 3;
      stage4a(sX, P.aCA + (size_t)(bg * 4) * DD, tid);
      __syncthreads();
      int col = cs * 64 + (tid & 63);
      int b = bg * 4 + (tid >> 6);
      const float* wp = P.wt8 + 7ull * DD * DD + col;  // 7:caWo
      float acc = gemv1(sX, wp, DD, tid);
      stg_a(&P.u2[(size_t)b * DD + col],
            acc + P.ca_bo[col] + ldg_a(&P.y1[(size_t)b * DD + col]));
    }
    gsync(P.flags, P.rel, round, tid, bid);

    // ---- Phase G: LN2(u2)=z ; u3=z+b2 (cs==0) ; hbuf=relu(z@W1+b1) ---------
    {
      int cs = bid & 31, bg = bid >> 5;
      stage4a(sX, P.u2 + (size_t)(bg * 4) * DD, tid);
      __syncthreads();
      ln4(sX, P.ln2w, P.ln2b, lm, li, tid);
      if (cs == 0) {
        float f0 = P.b2[tid], f1 = P.b2[tid + 256];
        #pragma unroll
        for (int r = 0; r < 4; r++) {
          stg_a(&P.u3[(size_t)(bg * 4 + r) * DD + tid], sX[r * DD + tid] + f0);
          stg_a(&P.u3[(size_t)(bg * 4 + r) * DD + tid + 256], sX[r * DD + tid + 256] + f1);
        }
      }
      int col = cs * 64 + (tid & 63);   // [0,2048)
      int b = bg * 4 + (tid >> 6);
      const float* wp = P.W1t + col;
      float acc = gemv1(sX, wp, DF, tid);
      stg_a(&P.hbuf[(size_t)b * DF + col], fmaxf(acc + P.b1[col], 0.f));
    }
    gsync(P.flags, P.rel, round, tid, bid);

    // ---- Phase H: u3 += hbuf@W2 (split-k x4, device-scope atomics) ---------
    {
      int cs = bid & 7, ks = (bid >> 3) & 3, bg = bid >> 5;
      #pragma unroll
      for (int q = 0; q < 8; q++) {
        int f = q * 256 + tid, r = f >> 9, c = f & 511;
        sX[f] = ldg_a(&P.hbuf[(size_t)(bg * 4 + r) * DF + ks * 512 + c]);
      }
      __syncthreads();
      int col = cs * 64 + (tid & 63);
      int b = bg * 4 + (tid >> 6);
      const float* wp = P.W2t + (size_t)(ks * 512) * DD + col;
      float acc = gemv1(sX, wp, DD, tid);
      atomicAdd(&P.u3[(size_t)b * DD + col], acc);
    }
    gsync(P.flags, P.rel, round, tid, bid);

    // ---- Phase I: nxt = LN3(u3)+ctx ; out ; xcur = nxt + pe[t+1] -----------
    if (bid < NB) {
      int b = bid, wv = tid >> 6, lane = tid & 63;
      float u0 = ldg_a(&P.u3[(size_t)b * DD + tid]);
      float u1v = ldg_a(&P.u3[(size_t)b * DD + tid + 256]);
      float s = u0 + u1v, q = u0 * u0 + u1v * u1v;
      #pragma unroll
      for (int m = 32; m >= 1; m >>= 1) { s += __shfl_xor(s, m); q += __shfl_xor(q, m); }
      if (lane == 0) { red[wv] = s; red[8 + wv] = q; }
      __syncthreads();
      if (tid == 0) {
        float ss = red[0] + red[1] + red[2] + red[3];
        float qq = red[8] + red[9] + red[10] + red[11];
        float mm = ss * (1.0f / 512.0f);
        red[16] = mm;
        red[17] = rsqrtf(qq * (1.0f / 512.0f) - mm * mm + 1e-5f);
      }
      __syncthreads();
      float mean = red[16], inv = red[17];
      float n0 = (u0 - mean) * inv * P.ln3w[tid] + P.ln3b[tid] +
                 ldg_a(&P.ctx[(size_t)b * DD + tid]);
      float n1 = (u1v - mean) * inv * P.ln3w[tid + 256] + P.ln3b[tid + 256] +
                 ldg_a(&P.ctx[(size_t)b * DD + tid + 256]);
      sX[tid] = n0; sX[tid + 256] = n1;
      float p0 = (t < TT - 1) ? P.pe[(size_t)(t + 1) * DD + tid] : 0.f;
      float p1 = (t < TT - 1) ? P.pe[(size_t)(t + 1) * DD + tid + 256] : 0.f;
      stg_a(&P.xcur[(size_t)b * DD + tid], n0 + p0);
      stg_a(&P.xcur[(size_t)b * DD + tid + 256], n1 + p1);
      __syncthreads();
      int c = tid >> 7, l = tid & 127;
      float a = 0.f;
      #pragma unroll
      for (int i = 0; i < 4; i++)
        a += sX[l + i * 128] * P.Wout[(size_t)c * DD + l + i * 128];
      #pragma unroll
      for (int m = 32; m >= 1; m >>= 1) a += __shfl_xor(a, m);
      if ((tid & 63) == 0) red[tid >> 6] = a;
      __syncthreads();
      if (tid == 0)   P.out[((size_t)b * TT + t) * 2 + 0] = red[0] + red[1] + P.bout[0];
      if (tid == 128) P.out[((size_t)b * TT + t) * 2 + 1] = red[2] + red[3] + P.bout[1];
    }
    gsync(P.flags, P.rel, round, tid, bid);
  }
}

// ---- precompute kernels -----------------------------------------------------
struct TPItem { const float* in; float* out; int R; int C; };
struct TPArgs { TPItem m[10]; };

__global__ __launch_bounds__(256) void transpose_many(TPArgs args) {
  const TPItem t = args.m[blockIdx.z];
  int r0 = blockIdx.x * 32, c0 = blockIdx.y * 32;
  if (r0 >= t.R || c0 >= t.C) return;
  __shared__ float tile[32][33];
  int tid = threadIdx.x;
  int i = tid >> 3, j4 = (tid & 7) * 4;
  float4 v = *(const float4*)(t.in + (size_t)(r0 + i) * t.C + c0 + j4);
  tile[i][j4] = v.x; tile[i][j4 + 1] = v.y; tile[i][j4 + 2] = v.z; tile[i][j4 + 3] = v.w;
  __syncthreads();
  float4 o;
  o.x = tile[j4][i]; o.y = tile[j4 + 1][i]; o.z = tile[j4 + 2][i]; o.w = tile[j4 + 3][i];
  *(float4*)(t.out + (size_t)(c0 + i) * t.R + r0 + j4) = o;
}

// K fp32 [b][n][d] -> bf16 transposed [b][d][n]
__global__ __launch_bounds__(256) void pack_kT(const float* __restrict__ Ks32,
                                               const float* __restrict__ Kc32,
                                               ushort_t* __restrict__ KsTb,
                                               ushort_t* __restrict__ KcTb) {
  int z = blockIdx.z;
  int b = z >> 1;
  const float* in = ((z & 1) ? Kc32 : Ks32) + (size_t)b * NN * DD;
  ushort_t* out = ((z & 1) ? KcTb : KsTb) + (size_t)b * NN * DD;
  int r0 = blockIdx.x * 32, c0 = blockIdx.y * 32;  // r over n(256), c over d(512)
  __shared__ float tile[32][33];
  int tid = threadIdx.x;
  int i = tid >> 3, j4 = (tid & 7) * 4;
  float4 v = *(const float4*)(in + (size_t)(r0 + i) * DD + c0 + j4);
  tile[i][j4] = v.x; tile[i][j4 + 1] = v.y; tile[i][j4 + 2] = v.z; tile[i][j4 + 3] = v.w;
  __syncthreads();
  ushort_t* op = out + (size_t)(c0 + i) * NN + r0 + j4;
  op[0] = f2bf(tile[j4][i]); op[1] = f2bf(tile[j4 + 1][i]);
  op[2] = f2bf(tile[j4 + 2][i]); op[3] = f2bf(tile[j4 + 3][i]);
}

// V fp32 -> bf16 elementwise
__global__ __launch_bounds__(256) void conv_v(const float* __restrict__ Vs32,
                                              const float* __restrict__ Vc32,
                                              ushort_t* __restrict__ VsB,
                                              ushort_t* __restrict__ VcB) {
  const float* src = blockIdx.y ? Vc32 : Vs32;
  ushort_t* dst = blockIdx.y ? VcB : VsB;
  size_t base = (size_t)blockIdx.x * 2048;
  #pragma unroll
  for (int q = 0; q < 2; q++) {
    size_t i = base + q * 1024 + threadIdx.x * 4;
    float4 v = *(const float4*)(src + i);
    dst[i] = f2bf(v.x); dst[i + 1] = f2bf(v.y);
    dst[i + 2] = f2bf(v.z); dst[i + 3] = f2bf(v.w);
  }
}

__global__ __launch_bounds__(256) void init_x(const float* __restrict__ hv0,
                                              const float* __restrict__ pe,
                                              float* __restrict__ xcur,
                                              unsigned* __restrict__ flags) {
  int i = blockIdx.x * 256 + threadIdx.x;
  xcur[i] = hv0[i] + pe[i & (DD - 1)];
  if (i < NBLK * FLAG_STRIDE + 32) flags[i] = 0u;
}

__global__ __launch_bounds__(256) void gemm_kv(
    const float* __restrict__ A,
    const float* __restrict__ W0, const float* __restrict__ W1_,
    const float* __restrict__ W2_, const float* __restrict__ W3_,
    const float* __restrict__ b0, const float* __restrict__ b1_,
    const float* __restrict__ b2_, const float* __restrict__ b3_,
    float* __restrict__ O0, float* __restrict__ O1,
    float* __restrict__ O2, float* __restrict__ O3) {
  __shared__ __align__(16) float As[8][128];
  __shared__ __align__(16) float Bs[8][128];
  int tid = threadIdx.x;
  int bx = blockIdx.x, by = blockIdx.y;
  int mm = bx >> 2;
  int col0 = (bx & 3) * 128;
  const float* W = mm == 0 ? W0 : mm == 1 ? W1_ : mm == 2 ? W2_ : W3_;
  const float* bias = mm == 0 ? b0 : mm == 1 ? b1_ : mm == 2 ? b2_ : b3_;
  float* O = mm == 0 ? O0 : mm == 1 ? O1 : mm == 2 ? O2 : O3;
  int tx = tid & 15, ty = tid >> 4;
  int m0 = by * 128;
  int lr = tid >> 1, lk = (tid & 1) * 4;
  const float* Ap = A + (size_t)(m0 + lr) * DD + lk;
  const float* Wp = W + (size_t)(col0 + lr) * DD + lk;
  float c[8][8] = {};
  for (int k0 = 0; k0 < DD; k0 += 8) {
    float4 av = *(const float4*)(Ap + k0);
    float4 wv = *(const float4*)(Wp + k0);
    __syncthreads();
    As[lk + 0][lr] = av.x; As[lk + 1][lr] = av.y; As[lk + 2][lr] = av.z; As[lk + 3][lr] = av.w;
    Bs[lk + 0][lr] = wv.x; Bs[lk + 1][lr] = wv.y; Bs[lk + 2][lr] = wv.z; Bs[lk + 3][lr] = wv.w;
    __syncthreads();
    #pragma unroll
    for (int k = 0; k < 8; k++) {
      float a[8], bb[8];
      *(float4*)&a[0] = *(const float4*)&As[k][ty * 8];
      *(float4*)&a[4] = *(const float4*)&As[k][ty * 8 + 4];
      *(float4*)&bb[0] = *(const float4*)&Bs[k][tx * 8];
      *(float4*)&bb[4] = *(const float4*)&Bs[k][tx * 8 + 4];
      #pragma unroll
      for (int i = 0; i < 8; i++)
        #pragma unroll
        for (int j = 0; j < 8; j++) c[i][j] += a[i] * bb[j];
    }
  }
  const float* bp = bias + col0 + tx * 8;
  for (int i = 0; i < 8; i++) {
    int row = m0 + ty * 8 + i;
    float* op = O + (size_t)row * DD + col0 + tx * 8;
    #pragma unroll
    for (int jq = 0; jq < 8; jq += 4) {
      float4 v;
      v.x = c[i][jq + 0] + bp[jq + 0];
      v.y = c[i][jq + 1] + bp[jq + 1];
      v.z = c[i][jq + 2] + bp[jq + 2];
      v.w = c[i][jq + 3] + bp[jq + 3];
      *(float4*)(op + jq) = v;
    }
  }
}

// ---------------------------------------------------------------------------
extern "C" void kernel_launch(void* const* d_in, const int* in_sizes, int n_in,
                              void* d_out, int out_size, void* d_ws, size_t ws_size,
                              hipStream_t stream) {
  const float* H_v_all = (const float*)d_in[0];
  const float* H_v0    = (const float*)d_in[1];
  const float* pe      = (const float*)d_in[2];
  const float* s_Wq = (const float*)d_in[3];
  const float* s_Wk = (const float*)d_in[4];
  const float* s_Wv = (const float*)d_in[5];
  const float* s_Wo = (const float*)d_in[6];
  const float* s_bq = (const float*)d_in[7];
  const float* s_bk = (const float*)d_in[8];
  const float* s_bv = (const float*)d_in[9];
  const float* s_bo = (const float*)d_in[10];
  const float* sa_Wq = (const float*)d_in[11];
  const float* sa_Wk = (const float*)d_in[12];
  const float* sa_Wv = (const float*)d_in[13];
  const float* sa_Wo = (const float*)d_in[14];
  const float* sa_bq = (const float*)d_in[15];
  const float* sa_bk = (const float*)d_in[16];
  const float* sa_bv = (const float*)d_in[17];
  const float* sa_bo = (const float*)d_in[18];
  const float* ca_Wq = (const float*)d_in[19];
  const float* ca_Wk = (const float*)d_in[20];
  const float* ca_Wv = (const float*)d_in[21];
  const float* ca_Wo = (const float*)d_in[22];
  const float* ca_bq = (const float*)d_in[23];
  const float* ca_bk = (const float*)d_in[24];
  const float* ca_bv = (const float*)d_in[25];
  const float* ca_bo = (const float*)d_in[26];
  const float* ln1w = (const float*)d_in[27];
  const float* ln1b = (const float*)d_in[28];
  const float* ln2w = (const float*)d_in[29];
  const float* ln2b = (const float*)d_in[30];
  const float* ln3w = (const float*)d_in[31];
  const float* ln3b = (const float*)d_in[32];
  const float* W1   = (const float*)d_in[33];
  const float* b1   = (const float*)d_in[34];
  const float* W2   = (const float*)d_in[35];
  const float* b2   = (const float*)d_in[36];
  const float* Wout = (const float*)d_in[37];
  const float* bout = (const float*)d_in[38];

  float* ws = (float*)d_ws;
  float* Ks32 = ws + OFF_KS32;
  float* Vs32 = ws + OFF_VS32;
  float* Kc32 = ws + OFF_KC32;
  float* Vc32 = ws + OFF_VC32;
  ushort_t* ub = (ushort_t*)(ws + OFF_BF);
  ushort_t* KsTb = ub + UOFF_KST;
  ushort_t* KcTb = ub + UOFF_KCT;
  ushort_t* VsB  = ub + UOFF_VS;
  ushort_t* VcB  = ub + UOFF_VC;
  float* wt8 = ws + OFF_WT;
  float* W1t = ws + OFF_W1T;
  float* W2t = ws + OFF_W2T;
  unsigned* flags = (unsigned*)(ws + OFF_FLG);

  // --- precompute -----------------------------------------------------------
  TPArgs tp;
  tp.m[0] = {sa_Wq, wt8 + 0ull * DD * DD, DD, DD};
  tp.m[1] = {sa_Wk, wt8 + 1ull * DD * DD, DD, DD};
  tp.m[2] = {sa_Wv, wt8 + 2ull * DD * DD, DD, DD};
  tp.m[3] = {s_Wq,  wt8 + 3ull * DD * DD, DD, DD};
  tp.m[4] = {sa_Wo, wt8 + 4ull * DD * DD, DD, DD};
  tp.m[5] = {s_Wo,  wt8 + 5ull * DD * DD, DD, DD};
  tp.m[6] = {ca_Wq, wt8 + 6ull * DD * DD, DD, DD};
  tp.m[7] = {ca_Wo, wt8 + 7ull * DD * DD, DD, DD};
  tp.m[8] = {W1, W1t, DF, DD};
  tp.m[9] = {W2, W2t, DD, DF};
  hipLaunchKernelGGL(transpose_many, dim3(64, 64, 10), dim3(256), 0, stream, tp);

  hipLaunchKernelGGL(gemm_kv, dim3(16, 64), dim3(256), 0, stream,
                     H_v_all, s_Wk, s_Wv, ca_Wk, ca_Wv,
                     s_bk, s_bv, ca_bk, ca_bv, Ks32, Vs32, Kc32, Vc32);

  hipLaunchKernelGGL(pack_kT, dim3(8, 16, 64), dim3(256), 0, stream,
                     Ks32, Kc32, KsTb, KcTb);
  hipLaunchKernelGGL(conv_v, dim3((unsigned)(SZ_KV / 2048), 2), dim3(256), 0, stream,
                     Vs32, Vc32, VsB, VcB);

  hipLaunchKernelGGL(init_x, dim3(64), dim3(256), 0, stream,
                     H_v0, pe, ws + OFF_X, flags);

  // --- persistent decode ----------------------------------------------------
  Params P;
  P.pe = pe;
  P.sa_bq = sa_bq; P.sa_bk = sa_bk; P.sa_bv = sa_bv; P.sa_bo = sa_bo;
  P.s_bq = s_bq; P.s_bo = s_bo; P.ca_bq = ca_bq; P.ca_bo = ca_bo;
  P.ln1w = ln1w; P.ln1b = ln1b; P.ln2w = ln2w; P.ln2b = ln2b;
  P.ln3w = ln3w; P.ln3b = ln3b;
  P.b1 = b1; P.b2 = b2; P.Wout = Wout; P.bout = bout;
  P.wt8 = wt8; P.W1t = W1t; P.W2t = W2t;
  P.KsTb = KsTb; P.KcTb = KcTb; P.VsB = VsB; P.VcB = VcB;
  P.Ksa = ws + OFF_KSA; P.Vsa = ws + OFF_VSA;
  P.xcur = ws + OFF_X;
  P.qsa = ws + OFF_QSA; P.qs = ws + OFF_QS;
  P.aSA = ws + OFF_ASA; P.aSP = ws + OFF_ASP; P.aCA = ws + OFF_ACA;
  P.u1 = ws + OFF_U1; P.y1 = ws + OFF_Y1; P.qc = ws + OFF_QC;
  P.u2 = ws + OFF_U2; P.ctx = ws + OFF_CTX; P.u3 = ws + OFF_U3;
  P.hbuf = ws + OFF_H;
  P.out = (float*)d_out;
  P.flags = flags;
  P.rel = flags + (size_t)NBLK * FLAG_STRIDE;

  void* kargs[] = { (void*)&P };
  hipLaunchCooperativeKernel((void*)decode_persistent, dim3(NBLK), dim3(256),
                             kargs, 0, stream);
}